// Round 12
// baseline (443.826 us; speedup 1.0000x reference)
//
#include <hip/hip_runtime.h>
#include <hip/hip_bf16.h>

typedef __bf16 bf16_t;
typedef __bf16 bf16x8 __attribute__((ext_vector_type(8)));
typedef __bf16 bf16x4 __attribute__((ext_vector_type(4)));
typedef float f32x4 __attribute__((ext_vector_type(4)));
typedef float f32x16 __attribute__((ext_vector_type(16)));

#define HIDDEN 2048
#define NHEADS 16
#define HD 128
#define NTOK 2048
#define BATCH 2
#define MROWS (BATCH*NTOK)
#define QKVCOLS (3*HIDDEN)

__device__ __forceinline__ void gload16(const void* g, void* l) {
    __builtin_amdgcn_global_load_lds(
        (const __attribute__((address_space(1))) void*)g,
        (__attribute__((address_space(3))) void*)l,
        16, 0, 0);
}

__device__ __forceinline__ unsigned int pack2bf(float lo, float hi2) {
    union { bf16_t h[2]; unsigned int u; } t;
    t.h[0] = (bf16_t)lo; t.h[1] = (bf16_t)hi2;
    return t.u;
}

// ---------------- fp32 -> bf16 elementwise (x) ----------------
__global__ __launch_bounds__(256) void cvt8_kernel(const float* __restrict__ in,
                                                   bf16_t* __restrict__ out, int n8) {
    int i = blockIdx.x * blockDim.x + threadIdx.x;
    if (i >= n8) return;
    const float4 a = *(const float4*)(in + (size_t)i * 8);
    const float4 b = *(const float4*)(in + (size_t)i * 8 + 4);
    bf16x8 r;
    r[0] = (bf16_t)a.x; r[1] = (bf16_t)a.y; r[2] = (bf16_t)a.z; r[3] = (bf16_t)a.w;
    r[4] = (bf16_t)b.x; r[5] = (bf16_t)b.y; r[6] = (bf16_t)b.z; r[7] = (bf16_t)b.w;
    *(bf16x8*)(out + (size_t)i * 8) = r;
}

// ---------------- fp32 KxN -> bf16 NxK transpose-convert ----------------
__global__ __launch_bounds__(256) void cvtT_kernel(const float* __restrict__ in,
                                                   bf16_t* __restrict__ out, int K, int N) {
    __shared__ float t[64][65];
    const int n0 = blockIdx.x * 64, k0 = blockIdx.y * 64;
    const int tid = threadIdx.x, c = tid & 63, r4 = tid >> 6;
#pragma unroll
    for (int rr = 0; rr < 64; rr += 4)
        t[rr + r4][c] = in[(size_t)(k0 + rr + r4) * N + n0 + c];
    __syncthreads();
#pragma unroll
    for (int rr = 0; rr < 64; rr += 4) {
        int nn = rr + r4;
        out[(size_t)(n0 + nn) * K + k0 + c] = (bf16_t)t[c][nn];
    }
}

// ---------------- 3-buffer pipelined GEMM: 128x256 tile (QKV proj) ----------------
template <typename OUTT>
__global__ __launch_bounds__(256, 2) void gemm_pipe(const bf16_t* __restrict__ A,
                                                    const bf16_t* __restrict__ Bt,
                                                    const float* __restrict__ bias,
                                                    OUTT* __restrict__ C,
                                                    int M, int N, int K) {
    __shared__ __align__(16) char lds[3][24576];  // per buf: A 8KB | B 16KB
    const int NKT = K >> 5;
    const int tid = threadIdx.x, wid = tid >> 6, lane = tid & 63;
    const int lr = lane & 15, lg = lane >> 4;
    const int nwg = gridDim.x, cpx = nwg >> 3;
    const int bid = blockIdx.x;
    const int swz = (bid & 7) * cpx + (bid >> 3);
    const int ntm = M >> 7;
    const int m0 = (swz % ntm) * 128, n0 = (swz / ntm) * 256;

    const int sc = (((tid & 3) ^ ((tid >> 3) & 3)) << 4);
    const int srow = tid >> 2;
    const char* pA0 = (const char*)A + ((size_t)(m0 + srow) * K) * 2 + sc;
    const char* pA1 = (const char*)A + ((size_t)(m0 + srow + 64) * K) * 2 + sc;
    const char* pB0 = (const char*)Bt + ((size_t)(n0 + srow) * K) * 2 + sc;
    const char* pB1 = (const char*)Bt + ((size_t)(n0 + srow + 64) * K) * 2 + sc;
    const char* pB2 = (const char*)Bt + ((size_t)(n0 + srow + 128) * K) * 2 + sc;
    const char* pB3 = (const char*)Bt + ((size_t)(n0 + srow + 192) * K) * 2 + sc;
    const int xoff = lr * 64 + ((lg ^ ((lr >> 1) & 3)) << 4);

    auto stage3a = [&](int kb, char* bp) {
        gload16(pA0 + kb, bp + tid * 16);
        gload16(pA1 + kb, bp + tid * 16 + 4096);
        gload16(pB0 + kb, bp + 8192 + tid * 16);
    };
    auto stage3b = [&](int kb, char* bp) {
        gload16(pB1 + kb, bp + 8192 + tid * 16 + 4096);
        gload16(pB2 + kb, bp + 8192 + tid * 16 + 8192);
        gload16(pB3 + kb, bp + 8192 + tid * 16 + 12288);
    };

    f32x4 acc[8][4];
#pragma unroll
    for (int m = 0; m < 8; ++m)
#pragma unroll
        for (int n = 0; n < 4; ++n) acc[m][n] = f32x4{0.f, 0.f, 0.f, 0.f};

    stage3a(0, lds[0]); stage3b(0, lds[0]);
    stage3a(64, lds[1]); stage3b(64, lds[1]);
    asm volatile("s_waitcnt vmcnt(6)" ::: "memory");
    __builtin_amdgcn_s_barrier();

    int cur = 0;
    for (int kt = 0; kt < NKT; ++kt) {
        const char* Al = lds[cur];
        const char* Bl = Al + 8192;
        int sb = cur + 2; if (sb >= 3) sb -= 3;
        char* sp = lds[sb];
        const bool st = (kt + 2) < NKT;
        const int kb = (kt + 2) << 6;

        bf16x8 bfr[4], afr[4];
#pragma unroll
        for (int n = 0; n < 4; ++n)
            bfr[n] = *(const bf16x8*)(Bl + wid * 4096 + n * 1024 + xoff);
#pragma unroll
        for (int m = 0; m < 4; ++m)
            afr[m] = *(const bf16x8*)(Al + m * 1024 + xoff);
        if (st) stage3a(kb, sp);
        __builtin_amdgcn_s_setprio(1);
#pragma unroll
        for (int m = 0; m < 4; ++m)
#pragma unroll
            for (int n = 0; n < 4; ++n)
                acc[m][n] = __builtin_amdgcn_mfma_f32_16x16x32_bf16(afr[m], bfr[n], acc[m][n], 0, 0, 0);
        __builtin_amdgcn_s_setprio(0);

#pragma unroll
        for (int m = 0; m < 4; ++m)
            afr[m] = *(const bf16x8*)(Al + (m + 4) * 1024 + xoff);
        if (st) stage3b(kb, sp);
        __builtin_amdgcn_s_setprio(1);
#pragma unroll
        for (int m = 0; m < 4; ++m)
#pragma unroll
            for (int n = 0; n < 4; ++n)
                acc[m + 4][n] = __builtin_amdgcn_mfma_f32_16x16x32_bf16(afr[m], bfr[n], acc[m + 4][n], 0, 0, 0);
        __builtin_amdgcn_s_setprio(0);

        if (kt < NKT - 1) {
            if (st) asm volatile("s_waitcnt vmcnt(6)" ::: "memory");
            else    asm volatile("s_waitcnt vmcnt(0)" ::: "memory");
            __builtin_amdgcn_s_barrier();
        }
        cur = cur + 1; if (cur >= 3) cur -= 3;
    }

    float bvals[4];
#pragma unroll
    for (int n = 0; n < 4; ++n) bvals[n] = bias[n0 + wid * 64 + n * 16 + lr];
#pragma unroll
    for (int m = 0; m < 8; ++m) {
        const size_t row = (size_t)(m0 + m * 16 + lg * 4);
#pragma unroll
        for (int n = 0; n < 4; ++n) {
            const int col = n0 + wid * 64 + n * 16 + lr;
#pragma unroll
            for (int i = 0; i < 4; ++i)
                C[(row + i) * N + col] = (OUTT)(acc[m][n][i] + bvals[n]);
        }
    }
}

// ---------------- 3-buffer pipelined GEMM: 128x128 tile (out-proj, grid 512) ----------------
__global__ __launch_bounds__(256, 2) void gemm_pipe_sq(const bf16_t* __restrict__ A,
                                                       const bf16_t* __restrict__ Bt,
                                                       const float* __restrict__ bias,
                                                       float* __restrict__ C,
                                                       int M, int N, int K) {
    __shared__ __align__(16) char lds[3][16384];  // per buf: A 8KB | B 8KB
    const int NKT = K >> 5;
    const int tid = threadIdx.x, wid = tid >> 6, lane = tid & 63;
    const int lr = lane & 15, lg = lane >> 4;
    const int wr = wid >> 1, wc = wid & 1;
    const int nwg = gridDim.x, cpx = nwg >> 3;
    const int bid = blockIdx.x;
    const int swz = (bid & 7) * cpx + (bid >> 3);
    const int ntm = M >> 7;
    const int m0 = (swz % ntm) * 128, n0 = (swz / ntm) * 128;

    const int sc = (((tid & 3) ^ ((tid >> 3) & 3)) << 4);
    const int srow = tid >> 2;
    const char* pA0 = (const char*)A + ((size_t)(m0 + srow) * K) * 2 + sc;
    const char* pA1 = (const char*)A + ((size_t)(m0 + srow + 64) * K) * 2 + sc;
    const char* pB0 = (const char*)Bt + ((size_t)(n0 + srow) * K) * 2 + sc;
    const char* pB1 = (const char*)Bt + ((size_t)(n0 + srow + 64) * K) * 2 + sc;
    const int xoff = lr * 64 + ((lg ^ ((lr >> 1) & 3)) << 4);

    auto stage4 = [&](int kb, char* bp) {
        gload16(pA0 + kb, bp + tid * 16);
        gload16(pA1 + kb, bp + tid * 16 + 4096);
        gload16(pB0 + kb, bp + 8192 + tid * 16);
        gload16(pB1 + kb, bp + 8192 + tid * 16 + 4096);
    };

    f32x4 acc[4][4];
#pragma unroll
    for (int m = 0; m < 4; ++m)
#pragma unroll
        for (int n = 0; n < 4; ++n) acc[m][n] = f32x4{0.f, 0.f, 0.f, 0.f};

    stage4(0, lds[0]);
    stage4(64, lds[1]);
    asm volatile("s_waitcnt vmcnt(4)" ::: "memory");
    __builtin_amdgcn_s_barrier();

    int cur = 0;
    for (int kt = 0; kt < NKT; ++kt) {
        const char* Al = lds[cur];
        const char* Bl = Al + 8192;
        int sb = cur + 2; if (sb >= 3) sb -= 3;
        char* sp = lds[sb];
        const bool st = (kt + 2) < NKT;

        bf16x8 bfr[4], afr[4];
#pragma unroll
        for (int n = 0; n < 4; ++n)
            bfr[n] = *(const bf16x8*)(Bl + wc * 4096 + n * 1024 + xoff);
#pragma unroll
        for (int m = 0; m < 4; ++m)
            afr[m] = *(const bf16x8*)(Al + wr * 4096 + m * 1024 + xoff);
        if (st) stage4((kt + 2) << 6, sp);
        __builtin_amdgcn_s_setprio(1);
#pragma unroll
        for (int m = 0; m < 4; ++m)
#pragma unroll
            for (int n = 0; n < 4; ++n)
                acc[m][n] = __builtin_amdgcn_mfma_f32_16x16x32_bf16(afr[m], bfr[n], acc[m][n], 0, 0, 0);
        __builtin_amdgcn_s_setprio(0);

        if (kt < NKT - 1) {
            if (st) asm volatile("s_waitcnt vmcnt(4)" ::: "memory");
            else    asm volatile("s_waitcnt vmcnt(0)" ::: "memory");
            __builtin_amdgcn_s_barrier();
        }
        cur = cur + 1; if (cur >= 3) cur -= 3;
    }

    float bvals[4];
#pragma unroll
    for (int n = 0; n < 4; ++n) bvals[n] = bias[n0 + wc * 64 + n * 16 + lr];
#pragma unroll
    for (int m = 0; m < 4; ++m) {
        const size_t row = (size_t)(m0 + wr * 64 + m * 16 + lg * 4);
#pragma unroll
        for (int n = 0; n < 4; ++n) {
            const int col = n0 + wc * 64 + n * 16 + lr;
#pragma unroll
            for (int i = 0; i < 4; ++i)
                C[(row + i) * N + col] = acc[m][n][i] + bvals[n];
        }
    }
}

// ---------------- cos/sin table: tab[n][j] = (cos, sin), 2048 x 64 ----------------
__global__ __launch_bounds__(256) void rope_cs(const int* __restrict__ Hp,
                                               const int* __restrict__ Wp,
                                               float2* __restrict__ tab) {
    const int idx = blockIdx.x * 256 + threadIdx.x;  // 512 blocks
    const int n = idx >> 6, j = idx & 63;
    const int Hh = *Hp, Ww = *Wp, HW = Hh * Ww;
    const int t = n / HW, rem = n % HW;
    const int hh = rem / Ww, w = rem % Ww;
    float pos = (j < 16) ? (float)t : (j < 40 ? (float)hh : (float)w);
    float inv = expf(-(float)j * (9.210340371976184f / 64.f));
    float ang = pos * inv;
    tab[idx] = make_float2(cosf(ang), sinf(ang));
}

// ---------------- fused MRoPE (q,k) + v transpose (table-driven) ----------------
__global__ __launch_bounds__(256) void rope_fused(const bf16_t* __restrict__ qkv,
                                                  bf16_t* __restrict__ qT,
                                                  bf16_t* __restrict__ kT,
                                                  bf16_t* __restrict__ vT,
                                                  const float2* __restrict__ tab) {
    const int blk = blockIdx.x;          // 1024 = 32 bh x 32 token-tiles
    const int bh = blk >> 5;
    const int n0 = (blk & 31) * 64;
    const int b = bh >> 4, h = bh & 15;
    const int tid = threadIdx.x;
    __shared__ bf16_t vt[64][132];       // [tok][d], +4 pad

    const float qscale = 0.08838834764831845f;  // 1/sqrt(128)
    const int jg = tid & 7, tn = tid >> 3;      // 32 tokens per pass
#pragma unroll
    for (int p = 0; p < 2; ++p) {
        const int tok = p * 32 + tn, n = n0 + tok;
        const bf16_t* base = qkv + (size_t)(b * NTOK + n) * QKVCOLS + h * HD + jg * 8;
        bf16x8 q1 = *(const bf16x8*)(base);
        bf16x8 q2 = *(const bf16x8*)(base + 64);
        bf16x8 k1 = *(const bf16x8*)(base + 2048);
        bf16x8 k2 = *(const bf16x8*)(base + 2048 + 64);
        bf16x8 v1 = *(const bf16x8*)(base + 4096);
        bf16x8 v2 = *(const bf16x8*)(base + 4096 + 64);
        union { float4 f4[4]; float2 f2[8]; } cs;
        const float4* cp4 = (const float4*)(tab + (size_t)n * 64 + jg * 8);
#pragma unroll
        for (int i = 0; i < 4; ++i) cs.f4[i] = cp4[i];
        bf16x8 oq1, oq2, ok1, ok2;
#pragma unroll
        for (int i = 0; i < 8; ++i) {
            float c = cs.f2[i].x, s = cs.f2[i].y;
            float a = (float)q1[i], bb = (float)q2[i];
            oq1[i] = (bf16_t)((a * c - bb * s) * qscale);
            oq2[i] = (bf16_t)((bb * c + a * s) * qscale);
            a = (float)k1[i]; bb = (float)k2[i];
            ok1[i] = (bf16_t)(a * c - bb * s);
            ok2[i] = (bf16_t)(bb * c + a * s);
        }
        const size_t qo = ((size_t)bh * NTOK + n) * HD + jg * 8;
        *(bf16x8*)(qT + qo) = oq1;
        *(bf16x8*)(qT + qo + 64) = oq2;
        *(bf16x8*)(kT + qo) = ok1;
        *(bf16x8*)(kT + qo + 64) = ok2;
        *(bf16x8*)&vt[tok][jg * 8] = v1;
        *(bf16x8*)&vt[tok][jg * 8 + 64] = v2;
    }
    __syncthreads();

    // vT[bh][d][NTOK]: thread (d = tid>>1, half = tid&1) writes 32 tokens
    const int d = tid >> 1, th = (tid & 1) * 32;
    bf16_t* orow = vT + ((size_t)bh * HD + d) * NTOK + n0 + th;
#pragma unroll
    for (int c = 0; c < 4; ++c) {
        bf16x8 tmp;
#pragma unroll
        for (int e = 0; e < 8; ++e) tmp[e] = vt[th + c * 8 + e][d];
        *(bf16x8*)(orow + c * 8) = tmp;
    }
}

// ---------------- flash attention v7: 8 waves, d-split, <=128 regs, 4 waves/SIMD ----------------
// Wave pair shares 32 q-rows; each wave duplicates QK^T+softmax (wave-local, no
// new sync) and computes PV only for its 64-d half (oa halves to 32 regs).
__global__ __launch_bounds__(512, 4) void attn_kernel(const bf16_t* __restrict__ qT,
                                                      const bf16_t* __restrict__ kT,
                                                      const bf16_t* __restrict__ vT,
                                                      bf16_t* __restrict__ outp) {
    __shared__ __align__(16) char lds[2][32768];  // per buf: K tile 16KB | V tile 16KB
    const int B = blockIdx.x;
    const int xcd = B & 7, jj = B >> 3;
    const int bh = xcd * 4 + (jj >> 4);
    const int q0 = (jj & 15) * 128;
    const int tid = threadIdx.x, wid = tid >> 6, lane = tid & 63;
    const int ql = lane & 31, hi = lane >> 5;
    const int pr = wid >> 1, dh = wid & 1;   // pair index, d-half

    const bf16_t* Q = qT + (size_t)bh * NTOK * HD;
    const char* Kb = (const char*)(kT + (size_t)bh * NTOK * HD);
    const char* Vb = (const char*)(vT + (size_t)bh * NTOK * HD);

    bf16x8 qf[8];
    {
        const bf16_t* qrow = Q + (size_t)(q0 + pr * 32 + ql) * HD + hi * 8;
#pragma unroll
        for (int kc = 0; kc < 8; ++kc) qf[kc] = *(const bf16x8*)(qrow + kc * 16);
    }
    f32x16 oa[2];
#pragma unroll
    for (int df = 0; df < 2; ++df)
#pragma unroll
        for (int r = 0; r < 16; ++r) oa[df][r] = 0.f;
    float m_run = -1e30f, l_run = 0.f;
    const float L2E = 1.44269504089f;

    const int sw = (ql & 7) << 4;
    int xk[8];
#pragma unroll
    for (int kc = 0; kc < 8; ++kc) xk[kc] = (kc * 32 + hi * 16) ^ sw;
    const int krb0 = ql * 256, krb1 = (32 + ql) * 256;
    int vrb[2];
#pragma unroll
    for (int df = 0; df < 2; ++df)
        vrb[df] = 16384 + ((dh * 2 + df) * 32 + ql) * 128;

    // staging: each of 8 waves stages 2KB of K and 2KB of V (4 gloads)
    const char* kgp[2];
    const char* vgp[2];
#pragma unroll
    for (int i = 0; i < 2; ++i) {
        int a = wid * 2048 + i * 1024 + lane * 16;
        int row = a >> 8;
        int col = (a & 255) ^ ((row & 7) << 4);
        kgp[i] = Kb + (size_t)row * 256 + col;
        int row2 = a >> 7;
        int col2 = (a & 127) ^ ((row2 & 7) << 4);
        vgp[i] = Vb + (size_t)row2 * (NTOK * 2) + col2;
    }
    const int lk0 = wid * 2048, lk1 = wid * 2048 + 1024;

    // prologue: issue tile 0 (iter-0's vmcnt covers it)
#pragma unroll
    for (int i = 0; i < 2; ++i) gload16(kgp[i], lds[0] + lk0 + i * 1024);
#pragma unroll
    for (int i = 0; i < 2; ++i) gload16(vgp[i], lds[0] + 16384 + lk0 + i * 1024);

    for (int t = 0; t < NTOK / 64; ++t) {
        const int buf = t & 1;
        if (t < NTOK / 64 - 1) {
            const size_t ko = (size_t)(t + 1) * 16384;
            const size_t vo = (size_t)(t + 1) * 128;
            char* db = lds[buf ^ 1];
#pragma unroll
            for (int i = 0; i < 2; ++i) gload16(kgp[i] + ko, db + lk0 + i * 1024);
#pragma unroll
            for (int i = 0; i < 2; ++i) gload16(vgp[i] + vo, db + 16384 + lk0 + i * 1024);
            asm volatile("s_waitcnt vmcnt(4)" ::: "memory");   // P(t) done; P(t+1) in flight
        } else {
            asm volatile("s_waitcnt vmcnt(0)" ::: "memory");
        }
        __builtin_amdgcn_s_barrier();
        const char* Kl = lds[buf];

#pragma unroll
        for (int half = 0; half < 2; ++half) {
            const int krb = half ? krb1 : krb0;
            f32x16 s;
#pragma unroll
            for (int r = 0; r < 16; ++r) s[r] = 0.f;
#pragma unroll
            for (int kc = 0; kc < 8; ++kc) {
                bf16x8 kf = *(const bf16x8*)(Kl + krb + xk[kc]);
                s = __builtin_amdgcn_mfma_f32_32x32x16_bf16(kf, qf[kc], s, 0, 0, 0);
            }

            float m8[8];
#pragma unroll
            for (int r = 0; r < 8; ++r) m8[r] = fmaxf(s[r], s[r + 8]);
#pragma unroll
            for (int st = 4; st >= 1; st >>= 1)
#pragma unroll
                for (int r = 0; r < st; ++r) m8[r] = fmaxf(m8[r], m8[r + st]);
            float mx = fmaxf(m8[0], __shfl_xor(m8[0], 32));
            if (__any(mx - m_run > 8.f)) {
                float mn = fmaxf(m_run, mx);
                float resc = __expf(m_run - mn);
                l_run *= resc;
#pragma unroll
                for (int df = 0; df < 2; ++df) oa[df] *= resc;
                m_run = mn;
            }
            const float mb = m_run * L2E;
#pragma unroll
            for (int r = 0; r < 16; ++r) s[r] = exp2f(fmaf(s[r], L2E, -mb));
            {
                float u[8];
#pragma unroll
                for (int r = 0; r < 8; ++r) u[r] = s[r] + s[r + 8];
#pragma unroll
                for (int st = 4; st >= 1; st >>= 1)
#pragma unroll
                    for (int r = 0; r < st; ++r) u[r] += u[r + st];
                l_run += u[0];
            }
            unsigned int pk[8];
#pragma unroll
            for (int m = 0; m < 8; ++m) pk[m] = pack2bf(s[2 * m], s[2 * m + 1]);

            // PV for this half, this wave's 64-d slice
#pragma unroll
            for (int c1 = 0; c1 < 2; ++c1) {
                unsigned int a0 = pk[4 * c1 + 0], b0 = pk[4 * c1 + 2];
                unsigned int a1 = pk[4 * c1 + 1], b1 = pk[4 * c1 + 3];
                asm("v_permlane32_swap_b32 %0, %1" : "+v"(a0), "+v"(b0));
                asm("v_permlane32_swap_b32 %0, %1" : "+v"(a1), "+v"(b1));
                union { unsigned int u[4]; bf16x8 v; } pb;
                pb.u[0] = a0; pb.u[1] = a1; pb.u[2] = b0; pb.u[3] = b1;
                const int kx = half * 2 + c1;
#pragma unroll
                for (int df = 0; df < 2; ++df) {
                    bf16x8 va = *(const bf16x8*)(Kl + vrb[df] + xk[kx]);
                    oa[df] = __builtin_amdgcn_mfma_f32_32x32x16_bf16(va, pb.v, oa[df], 0, 0, 0);
                }
            }
        }
        __builtin_amdgcn_s_barrier();
    }

    // epilogue: per-wave LDS transpose of 32q x 64d, then coalesced store
    float lt = l_run + __shfl_xor(l_run, 32);
    float inv = 1.f / lt;
    bf16_t* Ot = (bf16_t*)((char*)lds + wid * 4608);   // 32 x 72 bf16
#pragma unroll
    for (int df = 0; df < 2; ++df)
#pragma unroll
        for (int rg = 0; rg < 4; ++rg) {
            bf16x4 w;
#pragma unroll
            for (int i = 0; i < 4; ++i) w[i] = (bf16_t)(oa[df][rg * 4 + i] * inv);
            int d0 = df * 32 + rg * 8 + hi * 4;
            *(bf16x4*)&Ot[ql * 72 + d0] = w;
        }
    __builtin_amdgcn_s_waitcnt(0);
    const int qloc = lane >> 1, hf = lane & 1;
    const int b = bh >> 4, h = bh & 15;
    bf16_t* orow = outp + (size_t)(b * NTOK + q0 + pr * 32 + qloc) * HIDDEN
                   + h * HD + dh * 64 + hf * 32;
    const bf16_t* src = Ot + qloc * 72 + hf * 32;
    *(bf16x8*)(orow) = *(const bf16x8*)(src);
    *(bf16x8*)(orow + 8) = *(const bf16x8*)(src + 8);
    *(bf16x8*)(orow + 16) = *(const bf16x8*)(src + 16);
    *(bf16x8*)(orow + 24) = *(const bf16x8*)(src + 24);
}

extern "C" void kernel_launch(void* const* d_in, const int* in_sizes, int n_in,
                              void* d_out, int out_size, void* d_ws, size_t ws_size,
                              hipStream_t stream) {
    const float* x = (const float*)d_in[0];
    const float* w_qkv = (const float*)d_in[1];
    const float* b_qkv = (const float*)d_in[2];
    const float* w_proj = (const float*)d_in[3];
    const float* b_proj = (const float*)d_in[4];
    const int* Hp = (const int*)d_in[6];
    const int* Wp = (const int*)d_in[7];
    float* out = (float*)d_out;

    char* ws = (char*)d_ws;
    bf16_t* xb = (bf16_t*)(ws + 0);                       // 16 MiB  [4096][2048]
    bf16_t* wqkvT = (bf16_t*)(ws + 16777216);             // 24 MiB  [6144][2048]
    bf16_t* wprojT = (bf16_t*)(ws + 41943040);            // 8 MiB   [2048][2048]
    bf16_t* qkv = (bf16_t*)(ws + 50331648);               // 48 MiB  [4096][6144]
    bf16_t* qTb = (bf16_t*)(ws + 100663296);              // 16 MiB  [32][2048][128]
    bf16_t* kTb = (bf16_t*)(ws + 117440512);              // 16 MiB
    float2* tab = (float2*)(ws + 0);                      // 1 MiB, reuse xb after gemm1
    bf16_t* vT = (bf16_t*)(ws + 16777216);                // reuse wqkvT region after gemm1
    bf16_t* attno = (bf16_t*)(ws + 50331648);             // reuse qkv region after rope

    cvt8_kernel<<<4096, 256, 0, stream>>>(x, xb, 1048576);
    cvtT_kernel<<<dim3(96, 32), 256, 0, stream>>>(w_qkv, wqkvT, 2048, 6144);
    cvtT_kernel<<<dim3(32, 32), 256, 0, stream>>>(w_proj, wprojT, 2048, 2048);
    gemm_pipe<bf16_t><<<768, 256, 0, stream>>>(xb, wqkvT, b_qkv, qkv, MROWS, QKVCOLS, HIDDEN);
    rope_cs<<<512, 256, 0, stream>>>(Hp, Wp, tab);
    rope_fused<<<1024, 256, 0, stream>>>(qkv, qTb, kTb, vT, tab);
    attn_kernel<<<512, 512, 0, stream>>>(qTb, kTb, vT, attno);
    gemm_pipe_sq<<<512, 256, 0, stream>>>(attno, wprojT, b_proj, out, MROWS, HIDDEN, HIDDEN);
}

// Round 13
// 427.715 us; speedup vs baseline: 1.0377x; 1.0377x over previous
//
#include <hip/hip_runtime.h>
#include <hip/hip_bf16.h>

typedef __bf16 bf16_t;
typedef __bf16 bf16x8 __attribute__((ext_vector_type(8)));
typedef __bf16 bf16x4 __attribute__((ext_vector_type(4)));
typedef float f32x4 __attribute__((ext_vector_type(4)));
typedef float f32x16 __attribute__((ext_vector_type(16)));

#define HIDDEN 2048
#define NHEADS 16
#define HD 128
#define NTOK 2048
#define BATCH 2
#define MROWS (BATCH*NTOK)
#define QKVCOLS (3*HIDDEN)

__device__ __forceinline__ void gload16(const void* g, void* l) {
    __builtin_amdgcn_global_load_lds(
        (const __attribute__((address_space(1))) void*)g,
        (__attribute__((address_space(3))) void*)l,
        16, 0, 0);
}

__device__ __forceinline__ unsigned int pack2bf(float lo, float hi2) {
    union { bf16_t h[2]; unsigned int u; } t;
    t.h[0] = (bf16_t)lo; t.h[1] = (bf16_t)hi2;
    return t.u;
}

// ---------------- fp32 -> bf16 elementwise (x) ----------------
__global__ __launch_bounds__(256) void cvt8_kernel(const float* __restrict__ in,
                                                   bf16_t* __restrict__ out, int n8) {
    int i = blockIdx.x * blockDim.x + threadIdx.x;
    if (i >= n8) return;
    const float4 a = *(const float4*)(in + (size_t)i * 8);
    const float4 b = *(const float4*)(in + (size_t)i * 8 + 4);
    bf16x8 r;
    r[0] = (bf16_t)a.x; r[1] = (bf16_t)a.y; r[2] = (bf16_t)a.z; r[3] = (bf16_t)a.w;
    r[4] = (bf16_t)b.x; r[5] = (bf16_t)b.y; r[6] = (bf16_t)b.z; r[7] = (bf16_t)b.w;
    *(bf16x8*)(out + (size_t)i * 8) = r;
}

// ---------------- fp32 KxN -> bf16 NxK transpose-convert ----------------
__global__ __launch_bounds__(256) void cvtT_kernel(const float* __restrict__ in,
                                                   bf16_t* __restrict__ out, int K, int N) {
    __shared__ float t[64][65];
    const int n0 = blockIdx.x * 64, k0 = blockIdx.y * 64;
    const int tid = threadIdx.x, c = tid & 63, r4 = tid >> 6;
#pragma unroll
    for (int rr = 0; rr < 64; rr += 4)
        t[rr + r4][c] = in[(size_t)(k0 + rr + r4) * N + n0 + c];
    __syncthreads();
#pragma unroll
    for (int rr = 0; rr < 64; rr += 4) {
        int nn = rr + r4;
        out[(size_t)(n0 + nn) * K + k0 + c] = (bf16_t)t[c][nn];
    }
}

// ---------------- 3-buffer pipelined GEMM: 128x256 tile (QKV proj) ----------------
template <typename OUTT>
__global__ __launch_bounds__(256, 2) void gemm_pipe(const bf16_t* __restrict__ A,
                                                    const bf16_t* __restrict__ Bt,
                                                    const float* __restrict__ bias,
                                                    OUTT* __restrict__ C,
                                                    int M, int N, int K) {
    __shared__ __align__(16) char lds[3][24576];  // per buf: A 8KB | B 16KB
    const int NKT = K >> 5;
    const int tid = threadIdx.x, wid = tid >> 6, lane = tid & 63;
    const int lr = lane & 15, lg = lane >> 4;
    const int nwg = gridDim.x, cpx = nwg >> 3;
    const int bid = blockIdx.x;
    const int swz = (bid & 7) * cpx + (bid >> 3);
    const int ntm = M >> 7;
    const int m0 = (swz % ntm) * 128, n0 = (swz / ntm) * 256;

    const int sc = (((tid & 3) ^ ((tid >> 3) & 3)) << 4);
    const int srow = tid >> 2;
    const char* pA0 = (const char*)A + ((size_t)(m0 + srow) * K) * 2 + sc;
    const char* pA1 = (const char*)A + ((size_t)(m0 + srow + 64) * K) * 2 + sc;
    const char* pB0 = (const char*)Bt + ((size_t)(n0 + srow) * K) * 2 + sc;
    const char* pB1 = (const char*)Bt + ((size_t)(n0 + srow + 64) * K) * 2 + sc;
    const char* pB2 = (const char*)Bt + ((size_t)(n0 + srow + 128) * K) * 2 + sc;
    const char* pB3 = (const char*)Bt + ((size_t)(n0 + srow + 192) * K) * 2 + sc;
    const int xoff = lr * 64 + ((lg ^ ((lr >> 1) & 3)) << 4);

    auto stage3a = [&](int kb, char* bp) {
        gload16(pA0 + kb, bp + tid * 16);
        gload16(pA1 + kb, bp + tid * 16 + 4096);
        gload16(pB0 + kb, bp + 8192 + tid * 16);
    };
    auto stage3b = [&](int kb, char* bp) {
        gload16(pB1 + kb, bp + 8192 + tid * 16 + 4096);
        gload16(pB2 + kb, bp + 8192 + tid * 16 + 8192);
        gload16(pB3 + kb, bp + 8192 + tid * 16 + 12288);
    };

    f32x4 acc[8][4];
#pragma unroll
    for (int m = 0; m < 8; ++m)
#pragma unroll
        for (int n = 0; n < 4; ++n) acc[m][n] = f32x4{0.f, 0.f, 0.f, 0.f};

    stage3a(0, lds[0]); stage3b(0, lds[0]);
    stage3a(64, lds[1]); stage3b(64, lds[1]);
    asm volatile("s_waitcnt vmcnt(6)" ::: "memory");
    __builtin_amdgcn_s_barrier();

    int cur = 0;
    for (int kt = 0; kt < NKT; ++kt) {
        const char* Al = lds[cur];
        const char* Bl = Al + 8192;
        int sb = cur + 2; if (sb >= 3) sb -= 3;
        char* sp = lds[sb];
        const bool st = (kt + 2) < NKT;
        const int kb = (kt + 2) << 6;

        bf16x8 bfr[4], afr[4];
#pragma unroll
        for (int n = 0; n < 4; ++n)
            bfr[n] = *(const bf16x8*)(Bl + wid * 4096 + n * 1024 + xoff);
#pragma unroll
        for (int m = 0; m < 4; ++m)
            afr[m] = *(const bf16x8*)(Al + m * 1024 + xoff);
        if (st) stage3a(kb, sp);
        __builtin_amdgcn_s_setprio(1);
#pragma unroll
        for (int m = 0; m < 4; ++m)
#pragma unroll
            for (int n = 0; n < 4; ++n)
                acc[m][n] = __builtin_amdgcn_mfma_f32_16x16x32_bf16(afr[m], bfr[n], acc[m][n], 0, 0, 0);
        __builtin_amdgcn_s_setprio(0);

#pragma unroll
        for (int m = 0; m < 4; ++m)
            afr[m] = *(const bf16x8*)(Al + (m + 4) * 1024 + xoff);
        if (st) stage3b(kb, sp);
        __builtin_amdgcn_s_setprio(1);
#pragma unroll
        for (int m = 0; m < 4; ++m)
#pragma unroll
            for (int n = 0; n < 4; ++n)
                acc[m + 4][n] = __builtin_amdgcn_mfma_f32_16x16x32_bf16(afr[m], bfr[n], acc[m + 4][n], 0, 0, 0);
        __builtin_amdgcn_s_setprio(0);

        if (kt < NKT - 1) {
            if (st) asm volatile("s_waitcnt vmcnt(6)" ::: "memory");
            else    asm volatile("s_waitcnt vmcnt(0)" ::: "memory");
            __builtin_amdgcn_s_barrier();
        }
        cur = cur + 1; if (cur >= 3) cur -= 3;
    }

    float bvals[4];
#pragma unroll
    for (int n = 0; n < 4; ++n) bvals[n] = bias[n0 + wid * 64 + n * 16 + lr];
#pragma unroll
    for (int m = 0; m < 8; ++m) {
        const size_t row = (size_t)(m0 + m * 16 + lg * 4);
#pragma unroll
        for (int n = 0; n < 4; ++n) {
            const int col = n0 + wid * 64 + n * 16 + lr;
#pragma unroll
            for (int i = 0; i < 4; ++i)
                C[(row + i) * N + col] = (OUTT)(acc[m][n][i] + bvals[n]);
        }
    }
}

// ---------------- 3-buffer pipelined GEMM: 128x128 tile (out-proj, grid 512) ----------------
__global__ __launch_bounds__(256, 2) void gemm_pipe_sq(const bf16_t* __restrict__ A,
                                                       const bf16_t* __restrict__ Bt,
                                                       const float* __restrict__ bias,
                                                       float* __restrict__ C,
                                                       int M, int N, int K) {
    __shared__ __align__(16) char lds[3][16384];  // per buf: A 8KB | B 8KB
    const int NKT = K >> 5;
    const int tid = threadIdx.x, wid = tid >> 6, lane = tid & 63;
    const int lr = lane & 15, lg = lane >> 4;
    const int wr = wid >> 1, wc = wid & 1;
    const int nwg = gridDim.x, cpx = nwg >> 3;
    const int bid = blockIdx.x;
    const int swz = (bid & 7) * cpx + (bid >> 3);
    const int ntm = M >> 7;
    const int m0 = (swz % ntm) * 128, n0 = (swz / ntm) * 128;

    const int sc = (((tid & 3) ^ ((tid >> 3) & 3)) << 4);
    const int srow = tid >> 2;
    const char* pA0 = (const char*)A + ((size_t)(m0 + srow) * K) * 2 + sc;
    const char* pA1 = (const char*)A + ((size_t)(m0 + srow + 64) * K) * 2 + sc;
    const char* pB0 = (const char*)Bt + ((size_t)(n0 + srow) * K) * 2 + sc;
    const char* pB1 = (const char*)Bt + ((size_t)(n0 + srow + 64) * K) * 2 + sc;
    const int xoff = lr * 64 + ((lg ^ ((lr >> 1) & 3)) << 4);

    auto stage4 = [&](int kb, char* bp) {
        gload16(pA0 + kb, bp + tid * 16);
        gload16(pA1 + kb, bp + tid * 16 + 4096);
        gload16(pB0 + kb, bp + 8192 + tid * 16);
        gload16(pB1 + kb, bp + 8192 + tid * 16 + 4096);
    };

    f32x4 acc[4][4];
#pragma unroll
    for (int m = 0; m < 4; ++m)
#pragma unroll
        for (int n = 0; n < 4; ++n) acc[m][n] = f32x4{0.f, 0.f, 0.f, 0.f};

    stage4(0, lds[0]);
    stage4(64, lds[1]);
    asm volatile("s_waitcnt vmcnt(4)" ::: "memory");
    __builtin_amdgcn_s_barrier();

    int cur = 0;
    for (int kt = 0; kt < NKT; ++kt) {
        const char* Al = lds[cur];
        const char* Bl = Al + 8192;
        int sb = cur + 2; if (sb >= 3) sb -= 3;
        char* sp = lds[sb];
        const bool st = (kt + 2) < NKT;

        bf16x8 bfr[4], afr[4];
#pragma unroll
        for (int n = 0; n < 4; ++n)
            bfr[n] = *(const bf16x8*)(Bl + wc * 4096 + n * 1024 + xoff);
#pragma unroll
        for (int m = 0; m < 4; ++m)
            afr[m] = *(const bf16x8*)(Al + wr * 4096 + m * 1024 + xoff);
        if (st) stage4((kt + 2) << 6, sp);
        __builtin_amdgcn_s_setprio(1);
#pragma unroll
        for (int m = 0; m < 4; ++m)
#pragma unroll
            for (int n = 0; n < 4; ++n)
                acc[m][n] = __builtin_amdgcn_mfma_f32_16x16x32_bf16(afr[m], bfr[n], acc[m][n], 0, 0, 0);
        __builtin_amdgcn_s_setprio(0);

        if (kt < NKT - 1) {
            if (st) asm volatile("s_waitcnt vmcnt(4)" ::: "memory");
            else    asm volatile("s_waitcnt vmcnt(0)" ::: "memory");
            __builtin_amdgcn_s_barrier();
        }
        cur = cur + 1; if (cur >= 3) cur -= 3;
    }

    float bvals[4];
#pragma unroll
    for (int n = 0; n < 4; ++n) bvals[n] = bias[n0 + wc * 64 + n * 16 + lr];
#pragma unroll
    for (int m = 0; m < 4; ++m) {
        const size_t row = (size_t)(m0 + wr * 64 + m * 16 + lg * 4);
#pragma unroll
        for (int n = 0; n < 4; ++n) {
            const int col = n0 + wc * 64 + n * 16 + lr;
#pragma unroll
            for (int i = 0; i < 4; ++i)
                C[(row + i) * N + col] = acc[m][n][i] + bvals[n];
        }
    }
}

// ---------------- cos/sin table: tab[n][j] = (cos, sin), 2048 x 64 ----------------
__global__ __launch_bounds__(256) void rope_cs(const int* __restrict__ Hp,
                                               const int* __restrict__ Wp,
                                               float2* __restrict__ tab) {
    const int idx = blockIdx.x * 256 + threadIdx.x;  // 512 blocks
    const int n = idx >> 6, j = idx & 63;
    const int Hh = *Hp, Ww = *Wp, HW = Hh * Ww;
    const int t = n / HW, rem = n % HW;
    const int hh = rem / Ww, w = rem % Ww;
    float pos = (j < 16) ? (float)t : (j < 40 ? (float)hh : (float)w);
    float inv = expf(-(float)j * (9.210340371976184f / 64.f));
    float ang = pos * inv;
    tab[idx] = make_float2(cosf(ang), sinf(ang));
}

// ---------------- fused MRoPE (q,k) + v transpose (table-driven) ----------------
__global__ __launch_bounds__(256) void rope_fused(const bf16_t* __restrict__ qkv,
                                                  bf16_t* __restrict__ qT,
                                                  bf16_t* __restrict__ kT,
                                                  bf16_t* __restrict__ vT,
                                                  const float2* __restrict__ tab) {
    const int blk = blockIdx.x;          // 1024 = 32 bh x 32 token-tiles
    const int bh = blk >> 5;
    const int n0 = (blk & 31) * 64;
    const int b = bh >> 4, h = bh & 15;
    const int tid = threadIdx.x;
    __shared__ bf16_t vt[64][132];       // [tok][d], +4 pad

    const float qscale = 0.08838834764831845f;  // 1/sqrt(128)
    const int jg = tid & 7, tn = tid >> 3;      // 32 tokens per pass
#pragma unroll
    for (int p = 0; p < 2; ++p) {
        const int tok = p * 32 + tn, n = n0 + tok;
        const bf16_t* base = qkv + (size_t)(b * NTOK + n) * QKVCOLS + h * HD + jg * 8;
        bf16x8 q1 = *(const bf16x8*)(base);
        bf16x8 q2 = *(const bf16x8*)(base + 64);
        bf16x8 k1 = *(const bf16x8*)(base + 2048);
        bf16x8 k2 = *(const bf16x8*)(base + 2048 + 64);
        bf16x8 v1 = *(const bf16x8*)(base + 4096);
        bf16x8 v2 = *(const bf16x8*)(base + 4096 + 64);
        union { float4 f4[4]; float2 f2[8]; } cs;
        const float4* cp4 = (const float4*)(tab + (size_t)n * 64 + jg * 8);
#pragma unroll
        for (int i = 0; i < 4; ++i) cs.f4[i] = cp4[i];
        bf16x8 oq1, oq2, ok1, ok2;
#pragma unroll
        for (int i = 0; i < 8; ++i) {
            float c = cs.f2[i].x, s = cs.f2[i].y;
            float a = (float)q1[i], bb = (float)q2[i];
            oq1[i] = (bf16_t)((a * c - bb * s) * qscale);
            oq2[i] = (bf16_t)((bb * c + a * s) * qscale);
            a = (float)k1[i]; bb = (float)k2[i];
            ok1[i] = (bf16_t)(a * c - bb * s);
            ok2[i] = (bf16_t)(bb * c + a * s);
        }
        const size_t qo = ((size_t)bh * NTOK + n) * HD + jg * 8;
        *(bf16x8*)(qT + qo) = oq1;
        *(bf16x8*)(qT + qo + 64) = oq2;
        *(bf16x8*)(kT + qo) = ok1;
        *(bf16x8*)(kT + qo + 64) = ok2;
        *(bf16x8*)&vt[tok][jg * 8] = v1;
        *(bf16x8*)&vt[tok][jg * 8 + 64] = v2;
    }
    __syncthreads();

    // vT[bh][d][NTOK]: thread (d = tid>>1, half = tid&1) writes 32 tokens
    const int d = tid >> 1, th = (tid & 1) * 32;
    bf16_t* orow = vT + ((size_t)bh * HD + d) * NTOK + n0 + th;
#pragma unroll
    for (int c = 0; c < 4; ++c) {
        bf16x8 tmp;
#pragma unroll
        for (int e = 0; e < 8; ++e) tmp[e] = vt[th + c * 8 + e][d];
        *(bf16x8*)(orow + c * 8) = tmp;
    }
}

// ---------------- flash attention v8: no LDS staging — direct-from-cache fragments ----------------
// K/V for the 4 heads an XCD owns = 4MB = its L2; one tile's K+V = 32KB = L1.
// Each lane loads its MFMA fragment (16B) straight from global. No barriers,
// no vmcnt, no LDS traffic in the main loop; waves fully independent.
__global__ __launch_bounds__(256) void attn_kernel(const bf16_t* __restrict__ qT,
                                                   const bf16_t* __restrict__ kT,
                                                   const bf16_t* __restrict__ vT,
                                                   bf16_t* __restrict__ outp) {
    __shared__ __align__(16) bf16_t Ot[4][32 * 136];   // epilogue transpose only
    const int B = blockIdx.x;
    const int xcd = B & 7, jj = B >> 3;
    const int bh = xcd * 4 + (jj >> 4);
    const int q0 = (jj & 15) * 128;
    const int tid = threadIdx.x, wid = tid >> 6, lane = tid & 63;
    const int ql = lane & 31, hi = lane >> 5;

    const bf16_t* Q = qT + (size_t)bh * NTOK * HD;
    const char* Kb = (const char*)(kT + (size_t)bh * NTOK * HD);
    const char* Vb = (const char*)(vT + (size_t)bh * NTOK * HD);

    bf16x8 qf[8];
    {
        const bf16_t* qrow = Q + (size_t)(q0 + wid * 32 + ql) * HD + hi * 8;
#pragma unroll
        for (int kc = 0; kc < 8; ++kc) qf[kc] = *(const bf16x8*)(qrow + kc * 16);
    }
    f32x16 oa[4];
#pragma unroll
    for (int df = 0; df < 4; ++df)
#pragma unroll
        for (int r = 0; r < 16; ++r) oa[df][r] = 0.f;
    float m_run = -1e30f, l_run = 0.f;   // l_run: per-lane partial
    const float L2E = 1.44269504089f;

    // per-lane fragment base pointers (plain layout, no swizzle)
    const char* kp = Kb + (size_t)ql * 256 + hi * 16;    // + half*8192 + kc*32 + t*16384
    const char* vp = Vb + (size_t)ql * 4096 + hi * 16;   // + df*131072 + kx*32 + t*128

    for (int t = 0; t < NTOK / 64; ++t) {
        const char* kpt = kp + (size_t)t * 16384;
        const char* vpt = vp + (size_t)t * 128;

#pragma unroll
        for (int half = 0; half < 2; ++half) {
            const char* krow = kpt + half * 8192;
            f32x16 s;
#pragma unroll
            for (int r = 0; r < 16; ++r) s[r] = 0.f;
#pragma unroll
            for (int kc = 0; kc < 8; ++kc) {
                bf16x8 kf = *(const bf16x8*)(krow + kc * 32);
                s = __builtin_amdgcn_mfma_f32_32x32x16_bf16(kf, qf[kc], s, 0, 0, 0);
            }

            float m8[8];
#pragma unroll
            for (int r = 0; r < 8; ++r) m8[r] = fmaxf(s[r], s[r + 8]);
#pragma unroll
            for (int st = 4; st >= 1; st >>= 1)
#pragma unroll
                for (int r = 0; r < st; ++r) m8[r] = fmaxf(m8[r], m8[r + st]);
            float mx = fmaxf(m8[0], __shfl_xor(m8[0], 32));
            if (__any(mx - m_run > 8.f)) {
                float mn = fmaxf(m_run, mx);
                float resc = __expf(m_run - mn);
                l_run *= resc;
#pragma unroll
                for (int df = 0; df < 4; ++df) oa[df] *= resc;
                m_run = mn;
            }
            const float mb = m_run * L2E;
#pragma unroll
            for (int r = 0; r < 16; ++r) s[r] = exp2f(fmaf(s[r], L2E, -mb));
            {
                float u[8];
#pragma unroll
                for (int r = 0; r < 8; ++r) u[r] = s[r] + s[r + 8];
#pragma unroll
                for (int st = 4; st >= 1; st >>= 1)
#pragma unroll
                    for (int r = 0; r < st; ++r) u[r] += u[r + st];
                l_run += u[0];
            }
            unsigned int pk[8];
#pragma unroll
            for (int m = 0; m < 8; ++m) pk[m] = pack2bf(s[2 * m], s[2 * m + 1]);

#pragma unroll
            for (int c1 = 0; c1 < 2; ++c1) {
                unsigned int a0 = pk[4 * c1 + 0], b0 = pk[4 * c1 + 2];
                unsigned int a1 = pk[4 * c1 + 1], b1 = pk[4 * c1 + 3];
                asm("v_permlane32_swap_b32 %0, %1" : "+v"(a0), "+v"(b0));
                asm("v_permlane32_swap_b32 %0, %1" : "+v"(a1), "+v"(b1));
                union { unsigned int u[4]; bf16x8 v; } pb;
                pb.u[0] = a0; pb.u[1] = a1; pb.u[2] = b0; pb.u[3] = b1;
                const int kx = half * 2 + c1;
#pragma unroll
                for (int df = 0; df < 4; ++df) {
                    bf16x8 va = *(const bf16x8*)(vpt + df * 131072 + kx * 32);
                    oa[df] = __builtin_amdgcn_mfma_f32_32x32x16_bf16(va, pb.v, oa[df], 0, 0, 0);
                }
            }
        }
    }

    float lt = l_run + __shfl_xor(l_run, 32);
    float inv = 1.f / lt;
    bf16_t* Op = Ot[wid];
#pragma unroll
    for (int df = 0; df < 4; ++df)
#pragma unroll
        for (int rg = 0; rg < 4; ++rg) {
            bf16x4 w;
#pragma unroll
            for (int i = 0; i < 4; ++i) w[i] = (bf16_t)(oa[df][rg * 4 + i] * inv);
            int d0 = df * 32 + rg * 8 + hi * 4;
            *(bf16x4*)&Op[ql * 136 + d0] = w;
        }
    __builtin_amdgcn_s_waitcnt(0);   // drain ds_writes (same-wave region)
    const int qloc = lane >> 1, half = lane & 1;
    const int b = bh >> 4, h = bh & 15;
    bf16_t* orow = outp + (size_t)(b * NTOK + q0 + wid * 32 + qloc) * HIDDEN + h * HD + half * 64;
    const bf16_t* src = Op + qloc * 136 + half * 64;
#pragma unroll
    for (int c = 0; c < 8; ++c)
        *(bf16x8*)(orow + c * 8) = *(const bf16x8*)(src + c * 8);
}

extern "C" void kernel_launch(void* const* d_in, const int* in_sizes, int n_in,
                              void* d_out, int out_size, void* d_ws, size_t ws_size,
                              hipStream_t stream) {
    const float* x = (const float*)d_in[0];
    const float* w_qkv = (const float*)d_in[1];
    const float* b_qkv = (const float*)d_in[2];
    const float* w_proj = (const float*)d_in[3];
    const float* b_proj = (const float*)d_in[4];
    const int* Hp = (const int*)d_in[6];
    const int* Wp = (const int*)d_in[7];
    float* out = (float*)d_out;

    char* ws = (char*)d_ws;
    bf16_t* xb = (bf16_t*)(ws + 0);                       // 16 MiB  [4096][2048]
    bf16_t* wqkvT = (bf16_t*)(ws + 16777216);             // 24 MiB  [6144][2048]
    bf16_t* wprojT = (bf16_t*)(ws + 41943040);            // 8 MiB   [2048][2048]
    bf16_t* qkv = (bf16_t*)(ws + 50331648);               // 48 MiB  [4096][6144]
    bf16_t* qTb = (bf16_t*)(ws + 100663296);              // 16 MiB  [32][2048][128]
    bf16_t* kTb = (bf16_t*)(ws + 117440512);              // 16 MiB
    float2* tab = (float2*)(ws + 0);                      // 1 MiB, reuse xb after gemm1
    bf16_t* vT = (bf16_t*)(ws + 16777216);                // reuse wqkvT region after gemm1
    bf16_t* attno = (bf16_t*)(ws + 50331648);             // reuse qkv region after rope

    cvt8_kernel<<<4096, 256, 0, stream>>>(x, xb, 1048576);
    cvtT_kernel<<<dim3(96, 32), 256, 0, stream>>>(w_qkv, wqkvT, 2048, 6144);
    cvtT_kernel<<<dim3(32, 32), 256, 0, stream>>>(w_proj, wprojT, 2048, 2048);
    gemm_pipe<bf16_t><<<768, 256, 0, stream>>>(xb, wqkvT, b_qkv, qkv, MROWS, QKVCOLS, HIDDEN);
    rope_cs<<<512, 256, 0, stream>>>(Hp, Wp, tab);
    rope_fused<<<1024, 256, 0, stream>>>(qkv, qTb, kTb, vT, tab);
    attn_kernel<<<512, 256, 0, stream>>>(qTb, kTb, vT, attno);
    gemm_pipe_sq<<<512, 256, 0, stream>>>(attno, wprojT, b_proj, out, MROWS, HIDDEN, HIDDEN);
}

// Round 14
// 311.206 us; speedup vs baseline: 1.4262x; 1.3744x over previous
//
#include <hip/hip_runtime.h>
#include <hip/hip_bf16.h>

typedef __bf16 bf16_t;
typedef __bf16 bf16x8 __attribute__((ext_vector_type(8)));
typedef __bf16 bf16x4 __attribute__((ext_vector_type(4)));
typedef float f32x4 __attribute__((ext_vector_type(4)));
typedef float f32x16 __attribute__((ext_vector_type(16)));

#define HIDDEN 2048
#define NHEADS 16
#define HD 128
#define NTOK 2048
#define BATCH 2
#define MROWS (BATCH*NTOK)
#define QKVCOLS (3*HIDDEN)

__device__ __forceinline__ void gload16(const void* g, void* l) {
    __builtin_amdgcn_global_load_lds(
        (const __attribute__((address_space(1))) void*)g,
        (__attribute__((address_space(3))) void*)l,
        16, 0, 0);
}

__device__ __forceinline__ unsigned int pack2bf(float lo, float hi2) {
    union { bf16_t h[2]; unsigned int u; } t;
    t.h[0] = (bf16_t)lo; t.h[1] = (bf16_t)hi2;
    return t.u;
}

// ---------------- fp32 -> bf16 elementwise (x) ----------------
__global__ __launch_bounds__(256) void cvt8_kernel(const float* __restrict__ in,
                                                   bf16_t* __restrict__ out, int n8) {
    int i = blockIdx.x * blockDim.x + threadIdx.x;
    if (i >= n8) return;
    const float4 a = *(const float4*)(in + (size_t)i * 8);
    const float4 b = *(const float4*)(in + (size_t)i * 8 + 4);
    bf16x8 r;
    r[0] = (bf16_t)a.x; r[1] = (bf16_t)a.y; r[2] = (bf16_t)a.z; r[3] = (bf16_t)a.w;
    r[4] = (bf16_t)b.x; r[5] = (bf16_t)b.y; r[6] = (bf16_t)b.z; r[7] = (bf16_t)b.w;
    *(bf16x8*)(out + (size_t)i * 8) = r;
}

// ---------------- fp32 KxN -> bf16 NxK transpose-convert ----------------
__global__ __launch_bounds__(256) void cvtT_kernel(const float* __restrict__ in,
                                                   bf16_t* __restrict__ out, int K, int N) {
    __shared__ float t[64][65];
    const int n0 = blockIdx.x * 64, k0 = blockIdx.y * 64;
    const int tid = threadIdx.x, c = tid & 63, r4 = tid >> 6;
#pragma unroll
    for (int rr = 0; rr < 64; rr += 4)
        t[rr + r4][c] = in[(size_t)(k0 + rr + r4) * N + n0 + c];
    __syncthreads();
#pragma unroll
    for (int rr = 0; rr < 64; rr += 4) {
        int nn = rr + r4;
        out[(size_t)(n0 + nn) * K + k0 + c] = (bf16_t)t[c][nn];
    }
}

// ======== 256x256 8-phase pipelined GEMM (m201 geometry, race-proof schedule) ========
// BK=64, 8 waves (2M x 4N), 2 x 64KB LDS buffers. Per K-tile: 4 phases x 16 MFMA.
// Staging: A-halves of tile u+1 at ph1/ph2 (idle buffer); B-halves of tile u+2 at
// ph4 (regions died at ph3 barrier). vmcnt(4) once per tile, never 0 mid-loop.
__global__ __launch_bounds__(512, 2) void gemm8x(const bf16_t* __restrict__ A,
                                                 const bf16_t* __restrict__ Bt,
                                                 const float* __restrict__ bias,
                                                 bf16_t* __restrict__ C,
                                                 int M, int N, int K) {
    __shared__ __align__(16) char lds[2][65536];  // per buf: A 32KB | B 32KB
    const int NT = K >> 6;
    const int tid = threadIdx.x, wid = tid >> 6, lane = tid & 63;
    const int wr = wid >> 2, wc = wid & 3, lr = lane & 15, lg = lane >> 4;
    const int nwg = gridDim.x, cpx = nwg >> 3, bid = blockIdx.x;
    const int swz = (bid & 7) * cpx + (bid >> 3);
    const int ntm = M >> 8;
    const int m0 = (swz % ntm) << 8, n0 = (swz / ntm) << 8;

    const size_t KB2 = (size_t)K * 2;
    const int scol = (((tid & 7) ^ ((tid >> 3) & 7)) << 4);
    const char* pa = (const char*)A + (size_t)(m0 + (tid >> 3)) * KB2 + scol;
    const char* pb = (const char*)Bt + (size_t)(n0 + (tid >> 3)) * KB2 + scol;

    auto stA = [&](int ht, int t, char* bp) {  // 16KB half-tile, 2 loads/thread
        char* d = bp + ht * 16384 + tid * 16;
        const char* s = pa + (size_t)(ht * 128) * KB2 + (size_t)t * 128;
        gload16(s, d);
        gload16(s + 64 * KB2, d + 8192);
    };
    auto stB = [&](int ht, int t, char* bp) {
        char* d = bp + 32768 + ht * 16384 + tid * 16;
        const char* s = pb + (size_t)(ht * 128) * KB2 + (size_t)t * 128;
        gload16(s, d);
        gload16(s + 64 * KB2, d + 8192);
    };

    // fragment LDS offsets (row*128 + (ks*64+lg*16)^((row&7)<<4); row&7 == lr&7)
    const int xs = (lr & 7) << 4;
    int aof[2][8], bof[2][4];
#pragma unroll
    for (int ks = 0; ks < 2; ++ks) {
        const int kb = (ks * 64 + lg * 16) ^ xs;
#pragma unroll
        for (int m = 0; m < 8; ++m)
            aof[ks][m] = (wr * 128 + m * 16 + lr) * 128 + kb;
#pragma unroll
        for (int n = 0; n < 4; ++n)
            bof[ks][n] = 32768 + (wc * 64 + n * 16 + lr) * 128 + kb;
    }

    f32x4 acc[8][4];
#pragma unroll
    for (int m = 0; m < 8; ++m)
#pragma unroll
        for (int n = 0; n < 4; ++n) acc[m][n] = f32x4{0.f, 0.f, 0.f, 0.f};

    // prologue: tile0 full (buf0), tile1 B-halves (buf1); wait tile0, keep B(1) in flight
    stB(0, 0, lds[0]); stB(1, 0, lds[0]);
    stA(0, 0, lds[0]); stA(1, 0, lds[0]);
    stB(0, 1, lds[1]); stB(1, 1, lds[1]);
    asm volatile("s_waitcnt vmcnt(4)" ::: "memory");
    __builtin_amdgcn_s_barrier();

    for (int u = 0; u < NT; ++u) {
        char* cur = lds[u & 1];
        char* oth = lds[(u & 1) ^ 1];
        bf16x8 afr[4], bfr[4];

        // ---- phase 1: ks0, m0-3 (+ stage A-h0 of u+1 into idle buf) ----
#pragma unroll
        for (int n = 0; n < 4; ++n) bfr[n] = *(const bf16x8*)(cur + bof[0][n]);
#pragma unroll
        for (int m = 0; m < 4; ++m) afr[m] = *(const bf16x8*)(cur + aof[0][m]);
        if (u + 1 < NT) stA(0, u + 1, oth);
        __builtin_amdgcn_s_barrier();
        asm volatile("s_waitcnt lgkmcnt(0)" ::: "memory");
        __builtin_amdgcn_sched_barrier(0);
        __builtin_amdgcn_s_setprio(1);
#pragma unroll
        for (int m = 0; m < 4; ++m)
#pragma unroll
            for (int n = 0; n < 4; ++n)
                acc[m][n] = __builtin_amdgcn_mfma_f32_16x16x32_bf16(afr[m], bfr[n], acc[m][n], 0, 0, 0);
        __builtin_amdgcn_s_setprio(0);
        __builtin_amdgcn_s_barrier();

        // ---- phase 2: ks0, m4-7 (+ stage A-h1 of u+1) ----
#pragma unroll
        for (int m = 0; m < 4; ++m) afr[m] = *(const bf16x8*)(cur + aof[0][m + 4]);
        if (u + 1 < NT) stA(1, u + 1, oth);
        __builtin_amdgcn_s_barrier();
        asm volatile("s_waitcnt lgkmcnt(0)" ::: "memory");
        __builtin_amdgcn_sched_barrier(0);
        __builtin_amdgcn_s_setprio(1);
#pragma unroll
        for (int m = 0; m < 4; ++m)
#pragma unroll
            for (int n = 0; n < 4; ++n)
                acc[m + 4][n] = __builtin_amdgcn_mfma_f32_16x16x32_bf16(afr[m], bfr[n], acc[m + 4][n], 0, 0, 0);
        __builtin_amdgcn_s_setprio(0);
        __builtin_amdgcn_s_barrier();

        // ---- phase 3: ks1, m0-3 (no stage) ----
#pragma unroll
        for (int n = 0; n < 4; ++n) bfr[n] = *(const bf16x8*)(cur + bof[1][n]);
#pragma unroll
        for (int m = 0; m < 4; ++m) afr[m] = *(const bf16x8*)(cur + aof[1][m]);
        __builtin_amdgcn_s_barrier();
        asm volatile("s_waitcnt lgkmcnt(0)" ::: "memory");
        __builtin_amdgcn_sched_barrier(0);
        __builtin_amdgcn_s_setprio(1);
#pragma unroll
        for (int m = 0; m < 4; ++m)
#pragma unroll
            for (int n = 0; n < 4; ++n)
                acc[m][n] = __builtin_amdgcn_mfma_f32_16x16x32_bf16(afr[m], bfr[n], acc[m][n], 0, 0, 0);
        __builtin_amdgcn_s_setprio(0);
        __builtin_amdgcn_s_barrier();

        // ---- phase 4: ks1, m4-7 (+ stage both B-halves of u+2 into cur's dead B) ----
#pragma unroll
        for (int m = 0; m < 4; ++m) afr[m] = *(const bf16x8*)(cur + aof[1][m + 4]);
        if (u + 2 < NT) { stB(0, u + 2, cur); stB(1, u + 2, cur); }
        __builtin_amdgcn_s_barrier();
        asm volatile("s_waitcnt lgkmcnt(0)" ::: "memory");
        __builtin_amdgcn_sched_barrier(0);
        __builtin_amdgcn_s_setprio(1);
#pragma unroll
        for (int m = 0; m < 4; ++m)
#pragma unroll
            for (int n = 0; n < 4; ++n)
                acc[m + 4][n] = __builtin_amdgcn_mfma_f32_16x16x32_bf16(afr[m], bfr[n], acc[m + 4][n], 0, 0, 0);
        __builtin_amdgcn_s_setprio(0);
        if (u + 2 < NT) asm volatile("s_waitcnt vmcnt(4)" ::: "memory");
        else            asm volatile("s_waitcnt vmcnt(0)" ::: "memory");
        __builtin_amdgcn_s_barrier();
    }

    // epilogue
#pragma unroll
    for (int n = 0; n < 4; ++n) {
        const int col = n0 + wc * 64 + n * 16 + lr;
        const float bs = bias[col];
#pragma unroll
        for (int m = 0; m < 8; ++m) {
            const size_t row = (size_t)(m0 + wr * 128 + m * 16 + lg * 4);
#pragma unroll
            for (int i = 0; i < 4; ++i)
                C[(row + i) * N + col] = (bf16_t)(acc[m][n][i] + bs);
        }
    }
}

// ---------------- 3-buffer pipelined GEMM: 128x128 tile (out-proj, grid 512) ----------------
__global__ __launch_bounds__(256, 2) void gemm_pipe_sq(const bf16_t* __restrict__ A,
                                                       const bf16_t* __restrict__ Bt,
                                                       const float* __restrict__ bias,
                                                       float* __restrict__ C,
                                                       int M, int N, int K) {
    __shared__ __align__(16) char lds[3][16384];  // per buf: A 8KB | B 8KB
    const int NKT = K >> 5;
    const int tid = threadIdx.x, wid = tid >> 6, lane = tid & 63;
    const int lr = lane & 15, lg = lane >> 4;
    const int wr = wid >> 1, wc = wid & 1;
    const int nwg = gridDim.x, cpx = nwg >> 3;
    const int bid = blockIdx.x;
    const int swz = (bid & 7) * cpx + (bid >> 3);
    const int ntm = M >> 7;
    const int m0 = (swz % ntm) * 128, n0 = (swz / ntm) * 128;

    const int sc = (((tid & 3) ^ ((tid >> 3) & 3)) << 4);
    const int srow = tid >> 2;
    const char* pA0 = (const char*)A + ((size_t)(m0 + srow) * K) * 2 + sc;
    const char* pA1 = (const char*)A + ((size_t)(m0 + srow + 64) * K) * 2 + sc;
    const char* pB0 = (const char*)Bt + ((size_t)(n0 + srow) * K) * 2 + sc;
    const char* pB1 = (const char*)Bt + ((size_t)(n0 + srow + 64) * K) * 2 + sc;
    const int xoff = lr * 64 + ((lg ^ ((lr >> 1) & 3)) << 4);

    auto stage4 = [&](int kb, char* bp) {
        gload16(pA0 + kb, bp + tid * 16);
        gload16(pA1 + kb, bp + tid * 16 + 4096);
        gload16(pB0 + kb, bp + 8192 + tid * 16);
        gload16(pB1 + kb, bp + 8192 + tid * 16 + 4096);
    };

    f32x4 acc[4][4];
#pragma unroll
    for (int m = 0; m < 4; ++m)
#pragma unroll
        for (int n = 0; n < 4; ++n) acc[m][n] = f32x4{0.f, 0.f, 0.f, 0.f};

    stage4(0, lds[0]);
    stage4(64, lds[1]);
    asm volatile("s_waitcnt vmcnt(4)" ::: "memory");
    __builtin_amdgcn_s_barrier();

    int cur = 0;
    for (int kt = 0; kt < NKT; ++kt) {
        const char* Al = lds[cur];
        const char* Bl = Al + 8192;
        int sb = cur + 2; if (sb >= 3) sb -= 3;
        char* sp = lds[sb];
        const bool st = (kt + 2) < NKT;

        bf16x8 bfr[4], afr[4];
#pragma unroll
        for (int n = 0; n < 4; ++n)
            bfr[n] = *(const bf16x8*)(Bl + wc * 4096 + n * 1024 + xoff);
#pragma unroll
        for (int m = 0; m < 4; ++m)
            afr[m] = *(const bf16x8*)(Al + wr * 4096 + m * 1024 + xoff);
        if (st) stage4((kt + 2) << 6, sp);
        __builtin_amdgcn_s_setprio(1);
#pragma unroll
        for (int m = 0; m < 4; ++m)
#pragma unroll
            for (int n = 0; n < 4; ++n)
                acc[m][n] = __builtin_amdgcn_mfma_f32_16x16x32_bf16(afr[m], bfr[n], acc[m][n], 0, 0, 0);
        __builtin_amdgcn_s_setprio(0);

        if (kt < NKT - 1) {
            if (st) asm volatile("s_waitcnt vmcnt(4)" ::: "memory");
            else    asm volatile("s_waitcnt vmcnt(0)" ::: "memory");
            __builtin_amdgcn_s_barrier();
        }
        cur = cur + 1; if (cur >= 3) cur -= 3;
    }

    float bvals[4];
#pragma unroll
    for (int n = 0; n < 4; ++n) bvals[n] = bias[n0 + wc * 64 + n * 16 + lr];
#pragma unroll
    for (int m = 0; m < 4; ++m) {
        const size_t row = (size_t)(m0 + wr * 64 + m * 16 + lg * 4);
#pragma unroll
        for (int n = 0; n < 4; ++n) {
            const int col = n0 + wc * 64 + n * 16 + lr;
#pragma unroll
            for (int i = 0; i < 4; ++i)
                C[(row + i) * N + col] = acc[m][n][i] + bvals[n];
        }
    }
}

// ---------------- cos/sin table: tab[n][j] = (cos, sin), 2048 x 64 ----------------
__global__ __launch_bounds__(256) void rope_cs(const int* __restrict__ Hp,
                                               const int* __restrict__ Wp,
                                               float2* __restrict__ tab) {
    const int idx = blockIdx.x * 256 + threadIdx.x;  // 512 blocks
    const int n = idx >> 6, j = idx & 63;
    const int Hh = *Hp, Ww = *Wp, HW = Hh * Ww;
    const int t = n / HW, rem = n % HW;
    const int hh = rem / Ww, w = rem % Ww;
    float pos = (j < 16) ? (float)t : (j < 40 ? (float)hh : (float)w);
    float inv = expf(-(float)j * (9.210340371976184f / 64.f));
    float ang = pos * inv;
    tab[idx] = make_float2(cosf(ang), sinf(ang));
}

// ---------------- fused MRoPE (q,k) + v transpose (table-driven) ----------------
__global__ __launch_bounds__(256) void rope_fused(const bf16_t* __restrict__ qkv,
                                                  bf16_t* __restrict__ qT,
                                                  bf16_t* __restrict__ kT,
                                                  bf16_t* __restrict__ vT,
                                                  const float2* __restrict__ tab) {
    const int blk = blockIdx.x;          // 1024 = 32 bh x 32 token-tiles
    const int bh = blk >> 5;
    const int n0 = (blk & 31) * 64;
    const int b = bh >> 4, h = bh & 15;
    const int tid = threadIdx.x;
    __shared__ bf16_t vt[64][132];       // [tok][d], +4 pad

    const float qscale = 0.08838834764831845f;  // 1/sqrt(128)
    const int jg = tid & 7, tn = tid >> 3;      // 32 tokens per pass
#pragma unroll
    for (int p = 0; p < 2; ++p) {
        const int tok = p * 32 + tn, n = n0 + tok;
        const bf16_t* base = qkv + (size_t)(b * NTOK + n) * QKVCOLS + h * HD + jg * 8;
        bf16x8 q1 = *(const bf16x8*)(base);
        bf16x8 q2 = *(const bf16x8*)(base + 64);
        bf16x8 k1 = *(const bf16x8*)(base + 2048);
        bf16x8 k2 = *(const bf16x8*)(base + 2048 + 64);
        bf16x8 v1 = *(const bf16x8*)(base + 4096);
        bf16x8 v2 = *(const bf16x8*)(base + 4096 + 64);
        union { float4 f4[4]; float2 f2[8]; } cs;
        const float4* cp4 = (const float4*)(tab + (size_t)n * 64 + jg * 8);
#pragma unroll
        for (int i = 0; i < 4; ++i) cs.f4[i] = cp4[i];
        bf16x8 oq1, oq2, ok1, ok2;
#pragma unroll
        for (int i = 0; i < 8; ++i) {
            float c = cs.f2[i].x, s = cs.f2[i].y;
            float a = (float)q1[i], bb = (float)q2[i];
            oq1[i] = (bf16_t)((a * c - bb * s) * qscale);
            oq2[i] = (bf16_t)((bb * c + a * s) * qscale);
            a = (float)k1[i]; bb = (float)k2[i];
            ok1[i] = (bf16_t)(a * c - bb * s);
            ok2[i] = (bf16_t)(bb * c + a * s);
        }
        const size_t qo = ((size_t)bh * NTOK + n) * HD + jg * 8;
        *(bf16x8*)(qT + qo) = oq1;
        *(bf16x8*)(qT + qo + 64) = oq2;
        *(bf16x8*)(kT + qo) = ok1;
        *(bf16x8*)(kT + qo + 64) = ok2;
        *(bf16x8*)&vt[tok][jg * 8] = v1;
        *(bf16x8*)&vt[tok][jg * 8 + 64] = v2;
    }
    __syncthreads();

    // vT[bh][d][NTOK]: thread (d = tid>>1, half = tid&1) writes 32 tokens
    const int d = tid >> 1, th = (tid & 1) * 32;
    bf16_t* orow = vT + ((size_t)bh * HD + d) * NTOK + n0 + th;
#pragma unroll
    for (int c = 0; c < 4; ++c) {
        bf16x8 tmp;
#pragma unroll
        for (int e = 0; e < 8; ++e) tmp[e] = vt[th + c * 8 + e][d];
        *(bf16x8*)(orow + c * 8) = tmp;
    }
}

// ---------------- flash attention (R11 v6 — proven ~114us) ----------------
__global__ __launch_bounds__(256, 2) void attn_kernel(const bf16_t* __restrict__ qT,
                                                      const bf16_t* __restrict__ kT,
                                                      const bf16_t* __restrict__ vT,
                                                      bf16_t* __restrict__ outp) {
    __shared__ __align__(16) char lds[2][32768];  // per buf: K tile 16KB | V tile 16KB
    const int B = blockIdx.x;
    const int xcd = B & 7, jj = B >> 3;
    const int bh = xcd * 4 + (jj >> 4);
    const int q0 = (jj & 15) * 128;
    const int tid = threadIdx.x, wid = tid >> 6, lane = tid & 63;
    const int ql = lane & 31, hi = lane >> 5;

    const bf16_t* Q = qT + (size_t)bh * NTOK * HD;
    const char* Kb = (const char*)(kT + (size_t)bh * NTOK * HD);
    const char* Vb = (const char*)(vT + (size_t)bh * NTOK * HD);

    bf16x8 qf[8];
    {
        const bf16_t* qrow = Q + (size_t)(q0 + wid * 32 + ql) * HD + hi * 8;
#pragma unroll
        for (int kc = 0; kc < 8; ++kc) qf[kc] = *(const bf16x8*)(qrow + kc * 16);
    }
    f32x16 oa[4];
#pragma unroll
    for (int df = 0; df < 4; ++df)
#pragma unroll
        for (int r = 0; r < 16; ++r) oa[df][r] = 0.f;
    float m_run = -1e30f, l_run = 0.f;
    const float L2E = 1.44269504089f;

    const int sw = (ql & 7) << 4;
    int xk[8];
#pragma unroll
    for (int kc = 0; kc < 8; ++kc) xk[kc] = (kc * 32 + hi * 16) ^ sw;
    const int krb0 = ql * 256, krb1 = (32 + ql) * 256;
    int vrb[4];
#pragma unroll
    for (int df = 0; df < 4; ++df) vrb[df] = 16384 + (df * 32 + ql) * 128;

    const char* kgp[4];
    const char* vgp[4];
    const int ldso[4] = {wid * 4096, wid * 4096 + 1024, wid * 4096 + 2048, wid * 4096 + 3072};
#pragma unroll
    for (int i = 0; i < 4; ++i) {
        int a = wid * 4096 + i * 1024 + lane * 16;
        int row = a >> 8;
        int col = (a & 255) ^ ((row & 7) << 4);
        kgp[i] = Kb + (size_t)row * 256 + col;
        int row2 = a >> 7;
        int col2 = (a & 127) ^ ((row2 & 7) << 4);
        vgp[i] = Vb + (size_t)row2 * (NTOK * 2) + col2;
    }

#pragma unroll
    for (int i = 0; i < 4; ++i) gload16(kgp[i], lds[0] + ldso[i]);
#pragma unroll
    for (int i = 0; i < 4; ++i) gload16(vgp[i], lds[0] + 16384 + ldso[i]);

#pragma unroll 2
    for (int t = 0; t < NTOK / 64; ++t) {
        const int buf = t & 1;
        if (t < NTOK / 64 - 1) {
            const size_t ko = (size_t)(t + 1) * 16384;
            const size_t vo = (size_t)(t + 1) * 128;
            char* db = lds[buf ^ 1];
#pragma unroll
            for (int i = 0; i < 4; ++i) gload16(kgp[i] + ko, db + ldso[i]);
#pragma unroll
            for (int i = 0; i < 4; ++i) gload16(vgp[i] + vo, db + 16384 + ldso[i]);
            asm volatile("s_waitcnt vmcnt(8)" ::: "memory");
        } else {
            asm volatile("s_waitcnt vmcnt(0)" ::: "memory");
        }
        __builtin_amdgcn_s_barrier();
        const char* Kl = lds[buf];

#pragma unroll
        for (int half = 0; half < 2; ++half) {
            const int krb = half ? krb1 : krb0;
            f32x16 s;
#pragma unroll
            for (int r = 0; r < 16; ++r) s[r] = 0.f;
#pragma unroll
            for (int kc = 0; kc < 8; ++kc) {
                bf16x8 kf = *(const bf16x8*)(Kl + krb + xk[kc]);
                s = __builtin_amdgcn_mfma_f32_32x32x16_bf16(kf, qf[kc], s, 0, 0, 0);
            }
            f32x16 sv;
#pragma unroll
            for (int r = 0; r < 16; ++r) {
                float x = s[r];
                asm("v_mov_b32 %0, %1" : "=v"(sv[r]) : "v"(x));
            }

            float m8[8];
#pragma unroll
            for (int r = 0; r < 8; ++r) m8[r] = fmaxf(sv[r], sv[r + 8]);
#pragma unroll
            for (int st = 4; st >= 1; st >>= 1)
#pragma unroll
                for (int r = 0; r < st; ++r) m8[r] = fmaxf(m8[r], m8[r + st]);
            float mx = fmaxf(m8[0], __shfl_xor(m8[0], 32));
            if (__any(mx - m_run > 8.f)) {
                float mn = fmaxf(m_run, mx);
                float resc = __expf(m_run - mn);
                l_run *= resc;
#pragma unroll
                for (int df = 0; df < 4; ++df) oa[df] *= resc;
                m_run = mn;
            }
            const float mb = m_run * L2E;
#pragma unroll
            for (int r = 0; r < 16; ++r) sv[r] = exp2f(fmaf(sv[r], L2E, -mb));
            {
                float u[8];
#pragma unroll
                for (int r = 0; r < 8; ++r) u[r] = sv[r] + sv[r + 8];
#pragma unroll
                for (int st = 4; st >= 1; st >>= 1)
#pragma unroll
                    for (int r = 0; r < st; ++r) u[r] += u[r + st];
                l_run += u[0];
            }
            unsigned int pk[8];
#pragma unroll
            for (int m = 0; m < 8; ++m) pk[m] = pack2bf(sv[2 * m], sv[2 * m + 1]);

#pragma unroll
            for (int c1 = 0; c1 < 2; ++c1) {
                unsigned int a0 = pk[4 * c1 + 0], b0 = pk[4 * c1 + 2];
                unsigned int a1 = pk[4 * c1 + 1], b1 = pk[4 * c1 + 3];
                asm("v_permlane32_swap_b32 %0, %1" : "+v"(a0), "+v"(b0));
                asm("v_permlane32_swap_b32 %0, %1" : "+v"(a1), "+v"(b1));
                union { unsigned int u[4]; bf16x8 v; } pb;
                pb.u[0] = a0; pb.u[1] = a1; pb.u[2] = b0; pb.u[3] = b1;
                const int kx = half * 2 + c1;
#pragma unroll
                for (int df = 0; df < 4; ++df) {
                    bf16x8 va = *(const bf16x8*)(Kl + vrb[df] + xk[kx]);
                    oa[df] = __builtin_amdgcn_mfma_f32_32x32x16_bf16(va, pb.v, oa[df], 0, 0, 0);
                }
            }
        }
        __builtin_amdgcn_s_barrier();
    }

    float lt = l_run + __shfl_xor(l_run, 32);
    float inv = 1.f / lt;
    bf16_t* Ot = (bf16_t*)((char*)lds + wid * 8704);
#pragma unroll
    for (int df = 0; df < 4; ++df)
#pragma unroll
        for (int rg = 0; rg < 4; ++rg) {
            bf16x4 w;
#pragma unroll
            for (int i = 0; i < 4; ++i) w[i] = (bf16_t)(oa[df][rg * 4 + i] * inv);
            int d0 = df * 32 + rg * 8 + hi * 4;
            *(bf16x4*)&Ot[ql * 136 + d0] = w;
        }
    __builtin_amdgcn_s_waitcnt(0);
    const int qloc = lane >> 1, half = lane & 1;
    const int b = bh >> 4, h = bh & 15;
    bf16_t* orow = outp + (size_t)(b * NTOK + q0 + wid * 32 + qloc) * HIDDEN + h * HD + half * 64;
    const bf16_t* src = Ot + qloc * 136 + half * 64;
#pragma unroll
    for (int c = 0; c < 8; ++c)
        *(bf16x8*)(orow + c * 8) = *(const bf16x8*)(src + c * 8);
}

extern "C" void kernel_launch(void* const* d_in, const int* in_sizes, int n_in,
                              void* d_out, int out_size, void* d_ws, size_t ws_size,
                              hipStream_t stream) {
    const float* x = (const float*)d_in[0];
    const float* w_qkv = (const float*)d_in[1];
    const float* b_qkv = (const float*)d_in[2];
    const float* w_proj = (const float*)d_in[3];
    const float* b_proj = (const float*)d_in[4];
    const int* Hp = (const int*)d_in[6];
    const int* Wp = (const int*)d_in[7];
    float* out = (float*)d_out;

    char* ws = (char*)d_ws;
    bf16_t* xb = (bf16_t*)(ws + 0);                       // 16 MiB  [4096][2048]
    bf16_t* wqkvT = (bf16_t*)(ws + 16777216);             // 24 MiB  [6144][2048]
    bf16_t* wprojT = (bf16_t*)(ws + 41943040);            // 8 MiB   [2048][2048]
    bf16_t* qkv = (bf16_t*)(ws + 50331648);               // 48 MiB  [4096][6144]
    bf16_t* qTb = (bf16_t*)(ws + 100663296);              // 16 MiB  [32][2048][128]
    bf16_t* kTb = (bf16_t*)(ws + 117440512);              // 16 MiB
    float2* tab = (float2*)(ws + 0);                      // 1 MiB, reuse xb after gemm1
    bf16_t* vT = (bf16_t*)(ws + 16777216);                // reuse wqkvT region after gemm1
    bf16_t* attno = (bf16_t*)(ws + 50331648);             // reuse qkv region after rope

    cvt8_kernel<<<4096, 256, 0, stream>>>(x, xb, 1048576);
    cvtT_kernel<<<dim3(96, 32), 256, 0, stream>>>(w_qkv, wqkvT, 2048, 6144);
    cvtT_kernel<<<dim3(32, 32), 256, 0, stream>>>(w_proj, wprojT, 2048, 2048);
    gemm8x<<<384, 512, 0, stream>>>(xb, wqkvT, b_qkv, qkv, MROWS, QKVCOLS, HIDDEN);
    rope_cs<<<512, 256, 0, stream>>>(Hp, Wp, tab);
    rope_fused<<<1024, 256, 0, stream>>>(qkv, qTb, kTb, vT, tab);
    attn_kernel<<<512, 256, 0, stream>>>(qTb, kTb, vT, attno);
    gemm_pipe_sq<<<512, 256, 0, stream>>>(attno, wprojT, b_proj, out, MROWS, HIDDEN, HIDDEN);
}

// Round 15
// 283.168 us; speedup vs baseline: 1.5674x; 1.0990x over previous
//
#include <hip/hip_runtime.h>
#include <hip/hip_bf16.h>

typedef __bf16 bf16_t;
typedef __bf16 bf16x8 __attribute__((ext_vector_type(8)));
typedef __bf16 bf16x4 __attribute__((ext_vector_type(4)));
typedef float f32x4 __attribute__((ext_vector_type(4)));
typedef float f32x16 __attribute__((ext_vector_type(16)));

#define HIDDEN 2048
#define NHEADS 16
#define HD 128
#define NTOK 2048
#define BATCH 2
#define MROWS (BATCH*NTOK)
#define QKVCOLS (3*HIDDEN)

__device__ __forceinline__ void gload16(const void* g, void* l) {
    __builtin_amdgcn_global_load_lds(
        (const __attribute__((address_space(1))) void*)g,
        (__attribute__((address_space(3))) void*)l,
        16, 0, 0);
}

__device__ __forceinline__ unsigned int pack2bf(float lo, float hi2) {
    union { bf16_t h[2]; unsigned int u; } t;
    t.h[0] = (bf16_t)lo; t.h[1] = (bf16_t)hi2;
    return t.u;
}

// ---------------- fp32 -> bf16 elementwise (x) ----------------
__global__ __launch_bounds__(256) void cvt8_kernel(const float* __restrict__ in,
                                                   bf16_t* __restrict__ out, int n8) {
    int i = blockIdx.x * blockDim.x + threadIdx.x;
    if (i >= n8) return;
    const float4 a = *(const float4*)(in + (size_t)i * 8);
    const float4 b = *(const float4*)(in + (size_t)i * 8 + 4);
    bf16x8 r;
    r[0] = (bf16_t)a.x; r[1] = (bf16_t)a.y; r[2] = (bf16_t)a.z; r[3] = (bf16_t)a.w;
    r[4] = (bf16_t)b.x; r[5] = (bf16_t)b.y; r[6] = (bf16_t)b.z; r[7] = (bf16_t)b.w;
    *(bf16x8*)(out + (size_t)i * 8) = r;
}

// ---------------- fp32 KxN -> bf16 NxK transpose-convert ----------------
__global__ __launch_bounds__(256) void cvtT_kernel(const float* __restrict__ in,
                                                   bf16_t* __restrict__ out, int K, int N) {
    __shared__ float t[64][65];
    const int n0 = blockIdx.x * 64, k0 = blockIdx.y * 64;
    const int tid = threadIdx.x, c = tid & 63, r4 = tid >> 6;
#pragma unroll
    for (int rr = 0; rr < 64; rr += 4)
        t[rr + r4][c] = in[(size_t)(k0 + rr + r4) * N + n0 + c];
    __syncthreads();
#pragma unroll
    for (int rr = 0; rr < 64; rr += 4) {
        int nn = rr + r4;
        out[(size_t)(n0 + nn) * K + k0 + c] = (bf16_t)t[c][nn];
    }
}

// ---------------- cos/sin table: tab[n][j] = (cos, sin), 2048 x 64 ----------------
__global__ __launch_bounds__(256) void rope_cs(const int* __restrict__ Hp,
                                               const int* __restrict__ Wp,
                                               float2* __restrict__ tab) {
    const int idx = blockIdx.x * 256 + threadIdx.x;  // 512 blocks
    const int n = idx >> 6, j = idx & 63;
    const int Hh = *Hp, Ww = *Wp, HW = Hh * Ww;
    const int t = n / HW, rem = n % HW;
    const int hh = rem / Ww, w = rem % Ww;
    float pos = (j < 16) ? (float)t : (j < 40 ? (float)hh : (float)w);
    float inv = expf(-(float)j * (9.210340371976184f / 64.f));
    float ang = pos * inv;
    tab[idx] = make_float2(cosf(ang), sinf(ang));
}

// ======== QKV GEMM with fused RoPE + V-transpose epilogue ========
// Main loop = proven gemm_pipe (128x256, BK=32, 3 bufs, counted vmcnt(6)).
// Epilogue: tile -> LDS bounce -> which-uniform branch:
//   q/k: table RoPE, store [bh][n][d];  v: transpose, store [bh][d][n].
__global__ __launch_bounds__(256, 2) void gemm_qkv(const bf16_t* __restrict__ A,
                                                   const bf16_t* __restrict__ Bt,
                                                   const float* __restrict__ bias,
                                                   const float2* __restrict__ tab,
                                                   bf16_t* __restrict__ qT,
                                                   bf16_t* __restrict__ kT,
                                                   bf16_t* __restrict__ vT) {
    __shared__ __align__(16) char lds[3][24576];  // per buf: A 8KB | B 16KB
    const int M = MROWS, N = QKVCOLS, K = HIDDEN;
    const int NKT = K >> 5;
    const int tid = threadIdx.x, wid = tid >> 6, lane = tid & 63;
    const int lr = lane & 15, lg = lane >> 4;
    const int nwg = gridDim.x, cpx = nwg >> 3;
    const int bid = blockIdx.x;
    const int swz = (bid & 7) * cpx + (bid >> 3);
    const int ntm = M >> 7;
    const int m0 = (swz % ntm) * 128, n0 = (swz / ntm) * 256;

    const int sc = (((tid & 3) ^ ((tid >> 3) & 3)) << 4);
    const int srow = tid >> 2;
    const char* pA0 = (const char*)A + ((size_t)(m0 + srow) * K) * 2 + sc;
    const char* pA1 = (const char*)A + ((size_t)(m0 + srow + 64) * K) * 2 + sc;
    const char* pB0 = (const char*)Bt + ((size_t)(n0 + srow) * K) * 2 + sc;
    const char* pB1 = (const char*)Bt + ((size_t)(n0 + srow + 64) * K) * 2 + sc;
    const char* pB2 = (const char*)Bt + ((size_t)(n0 + srow + 128) * K) * 2 + sc;
    const char* pB3 = (const char*)Bt + ((size_t)(n0 + srow + 192) * K) * 2 + sc;
    const int xoff = lr * 64 + ((lg ^ ((lr >> 1) & 3)) << 4);

    auto stage3a = [&](int kb, char* bp) {
        gload16(pA0 + kb, bp + tid * 16);
        gload16(pA1 + kb, bp + tid * 16 + 4096);
        gload16(pB0 + kb, bp + 8192 + tid * 16);
    };
    auto stage3b = [&](int kb, char* bp) {
        gload16(pB1 + kb, bp + 8192 + tid * 16 + 4096);
        gload16(pB2 + kb, bp + 8192 + tid * 16 + 8192);
        gload16(pB3 + kb, bp + 8192 + tid * 16 + 12288);
    };

    f32x4 acc[8][4];
#pragma unroll
    for (int m = 0; m < 8; ++m)
#pragma unroll
        for (int n = 0; n < 4; ++n) acc[m][n] = f32x4{0.f, 0.f, 0.f, 0.f};

    stage3a(0, lds[0]); stage3b(0, lds[0]);
    stage3a(64, lds[1]); stage3b(64, lds[1]);
    asm volatile("s_waitcnt vmcnt(6)" ::: "memory");
    __builtin_amdgcn_s_barrier();

    int cur = 0;
    for (int kt = 0; kt < NKT; ++kt) {
        const char* Al = lds[cur];
        const char* Bl = Al + 8192;
        int sb = cur + 2; if (sb >= 3) sb -= 3;
        char* sp = lds[sb];
        const bool st = (kt + 2) < NKT;
        const int kb = (kt + 2) << 6;

        bf16x8 bfr[4], afr[4];
#pragma unroll
        for (int n = 0; n < 4; ++n)
            bfr[n] = *(const bf16x8*)(Bl + wid * 4096 + n * 1024 + xoff);
#pragma unroll
        for (int m = 0; m < 4; ++m)
            afr[m] = *(const bf16x8*)(Al + m * 1024 + xoff);
        if (st) stage3a(kb, sp);
        __builtin_amdgcn_s_setprio(1);
#pragma unroll
        for (int m = 0; m < 4; ++m)
#pragma unroll
            for (int n = 0; n < 4; ++n)
                acc[m][n] = __builtin_amdgcn_mfma_f32_16x16x32_bf16(afr[m], bfr[n], acc[m][n], 0, 0, 0);
        __builtin_amdgcn_s_setprio(0);

#pragma unroll
        for (int m = 0; m < 4; ++m)
            afr[m] = *(const bf16x8*)(Al + (m + 4) * 1024 + xoff);
        if (st) stage3b(kb, sp);
        __builtin_amdgcn_s_setprio(1);
#pragma unroll
        for (int m = 0; m < 4; ++m)
#pragma unroll
            for (int n = 0; n < 4; ++n)
                acc[m + 4][n] = __builtin_amdgcn_mfma_f32_16x16x32_bf16(afr[m], bfr[n], acc[m + 4][n], 0, 0, 0);
        __builtin_amdgcn_s_setprio(0);

        if (kt < NKT - 1) {
            if (st) asm volatile("s_waitcnt vmcnt(6)" ::: "memory");
            else    asm volatile("s_waitcnt vmcnt(0)" ::: "memory");
            __builtin_amdgcn_s_barrier();
        }
        cur = cur + 1; if (cur >= 3) cur -= 3;
    }

    // ---- fused epilogue: acc -> LDS tile -> RoPE / transpose stores ----
    __syncthreads();                       // all waves done with staging LDS
    bf16_t* T = (bf16_t*)lds;              // [128][264] = 67584 B < 73728 B
    const int TW = 264;
    float bvals[4];
#pragma unroll
    for (int n = 0; n < 4; ++n) bvals[n] = bias[n0 + wid * 64 + n * 16 + lr];
#pragma unroll
    for (int m = 0; m < 8; ++m)
#pragma unroll
        for (int n = 0; n < 4; ++n)
#pragma unroll
            for (int i = 0; i < 4; ++i)
                T[(m * 16 + lg * 4 + i) * TW + wid * 64 + n * 16 + lr] =
                    (bf16_t)(acc[m][n][i] + bvals[n]);
    __syncthreads();

    const int which = n0 >> 11;            // 0=q, 1=k, 2=v (tile never spans)
    const int hbase = (n0 & 2047) >> 7;    // first head in tile (2 heads/tile)
    const int b = m0 >> 11, tokbase = m0 & 2047;

    if (which < 2) {
        bf16_t* dst = which ? kT : qT;
        const float qs = which ? 1.f : 0.08838834764831845f;  // 1/sqrt(128) on q
        const int jg = tid & 7, rl = tid >> 3;
#pragma unroll
        for (int p = 0; p < 4; ++p) {
            const int tok = p * 32 + rl;
            const int n_tok = tokbase + tok;
            union { float4 f4[4]; float2 f2[8]; } cs;
            const float4* cp4 = (const float4*)(tab + (size_t)n_tok * 64 + jg * 8);
#pragma unroll
            for (int i = 0; i < 4; ++i) cs.f4[i] = cp4[i];
#pragma unroll
            for (int h2 = 0; h2 < 2; ++h2) {
                bf16x8 lo = *(const bf16x8*)&T[tok * TW + h2 * 128 + jg * 8];
                bf16x8 hi = *(const bf16x8*)&T[tok * TW + h2 * 128 + 64 + jg * 8];
                bf16x8 olo, ohi;
#pragma unroll
                for (int i = 0; i < 8; ++i) {
                    float c = cs.f2[i].x, s = cs.f2[i].y;
                    float a = (float)lo[i], bb = (float)hi[i];
                    olo[i] = (bf16_t)((a * c - bb * s) * qs);
                    ohi[i] = (bf16_t)((bb * c + a * s) * qs);
                }
                const int bh = b * NHEADS + hbase + h2;
                const size_t o = ((size_t)bh * NTOK + n_tok) * HD + jg * 8;
                *(bf16x8*)(dst + o) = olo;
                *(bf16x8*)(dst + o + 64) = ohi;
            }
        }
    } else {
        const int d = tid >> 1, th = (tid & 1) * 64;
#pragma unroll
        for (int h2 = 0; h2 < 2; ++h2) {
            const int bh = b * NHEADS + hbase + h2;
            bf16_t* orow = vT + ((size_t)bh * HD + d) * NTOK + tokbase + th;
#pragma unroll
            for (int c8 = 0; c8 < 8; ++c8) {
                bf16x8 tmp;
#pragma unroll
                for (int e = 0; e < 8; ++e)
                    tmp[e] = T[(th + c8 * 8 + e) * TW + h2 * 128 + d];
                *(bf16x8*)(orow + c8 * 8) = tmp;
            }
        }
    }
}

// ---------------- 3-buffer pipelined GEMM: 128x128 tile (out-proj, grid 512) ----------------
__global__ __launch_bounds__(256, 2) void gemm_pipe_sq(const bf16_t* __restrict__ A,
                                                       const bf16_t* __restrict__ Bt,
                                                       const float* __restrict__ bias,
                                                       float* __restrict__ C,
                                                       int M, int N, int K) {
    __shared__ __align__(16) char lds[3][16384];  // per buf: A 8KB | B 8KB
    const int NKT = K >> 5;
    const int tid = threadIdx.x, wid = tid >> 6, lane = tid & 63;
    const int lr = lane & 15, lg = lane >> 4;
    const int wr = wid >> 1, wc = wid & 1;
    const int nwg = gridDim.x, cpx = nwg >> 3;
    const int bid = blockIdx.x;
    const int swz = (bid & 7) * cpx + (bid >> 3);
    const int ntm = M >> 7;
    const int m0 = (swz % ntm) * 128, n0 = (swz / ntm) * 128;

    const int sc = (((tid & 3) ^ ((tid >> 3) & 3)) << 4);
    const int srow = tid >> 2;
    const char* pA0 = (const char*)A + ((size_t)(m0 + srow) * K) * 2 + sc;
    const char* pA1 = (const char*)A + ((size_t)(m0 + srow + 64) * K) * 2 + sc;
    const char* pB0 = (const char*)Bt + ((size_t)(n0 + srow) * K) * 2 + sc;
    const char* pB1 = (const char*)Bt + ((size_t)(n0 + srow + 64) * K) * 2 + sc;
    const int xoff = lr * 64 + ((lg ^ ((lr >> 1) & 3)) << 4);

    auto stage4 = [&](int kb, char* bp) {
        gload16(pA0 + kb, bp + tid * 16);
        gload16(pA1 + kb, bp + tid * 16 + 4096);
        gload16(pB0 + kb, bp + 8192 + tid * 16);
        gload16(pB1 + kb, bp + 8192 + tid * 16 + 4096);
    };

    f32x4 acc[4][4];
#pragma unroll
    for (int m = 0; m < 4; ++m)
#pragma unroll
        for (int n = 0; n < 4; ++n) acc[m][n] = f32x4{0.f, 0.f, 0.f, 0.f};

    stage4(0, lds[0]);
    stage4(64, lds[1]);
    asm volatile("s_waitcnt vmcnt(4)" ::: "memory");
    __builtin_amdgcn_s_barrier();

    int cur = 0;
    for (int kt = 0; kt < NKT; ++kt) {
        const char* Al = lds[cur];
        const char* Bl = Al + 8192;
        int sb = cur + 2; if (sb >= 3) sb -= 3;
        char* sp = lds[sb];
        const bool st = (kt + 2) < NKT;

        bf16x8 bfr[4], afr[4];
#pragma unroll
        for (int n = 0; n < 4; ++n)
            bfr[n] = *(const bf16x8*)(Bl + wc * 4096 + n * 1024 + xoff);
#pragma unroll
        for (int m = 0; m < 4; ++m)
            afr[m] = *(const bf16x8*)(Al + wr * 4096 + m * 1024 + xoff);
        if (st) stage4((kt + 2) << 6, sp);
        __builtin_amdgcn_s_setprio(1);
#pragma unroll
        for (int m = 0; m < 4; ++m)
#pragma unroll
            for (int n = 0; n < 4; ++n)
                acc[m][n] = __builtin_amdgcn_mfma_f32_16x16x32_bf16(afr[m], bfr[n], acc[m][n], 0, 0, 0);
        __builtin_amdgcn_s_setprio(0);

        if (kt < NKT - 1) {
            if (st) asm volatile("s_waitcnt vmcnt(4)" ::: "memory");
            else    asm volatile("s_waitcnt vmcnt(0)" ::: "memory");
            __builtin_amdgcn_s_barrier();
        }
        cur = cur + 1; if (cur >= 3) cur -= 3;
    }

    float bvals[4];
#pragma unroll
    for (int n = 0; n < 4; ++n) bvals[n] = bias[n0 + wc * 64 + n * 16 + lr];
#pragma unroll
    for (int m = 0; m < 4; ++m) {
        const size_t row = (size_t)(m0 + wr * 64 + m * 16 + lg * 4);
#pragma unroll
        for (int n = 0; n < 4; ++n) {
            const int col = n0 + wc * 64 + n * 16 + lr;
#pragma unroll
            for (int i = 0; i < 4; ++i)
                C[(row + i) * N + col] = acc[m][n][i] + bvals[n];
        }
    }
}

// ---------------- flash attention (proven ~114us) ----------------
__global__ __launch_bounds__(256, 2) void attn_kernel(const bf16_t* __restrict__ qT,
                                                      const bf16_t* __restrict__ kT,
                                                      const bf16_t* __restrict__ vT,
                                                      bf16_t* __restrict__ outp) {
    __shared__ __align__(16) char lds[2][32768];  // per buf: K tile 16KB | V tile 16KB
    const int B = blockIdx.x;
    const int xcd = B & 7, jj = B >> 3;
    const int bh = xcd * 4 + (jj >> 4);
    const int q0 = (jj & 15) * 128;
    const int tid = threadIdx.x, wid = tid >> 6, lane = tid & 63;
    const int ql = lane & 31, hi = lane >> 5;

    const bf16_t* Q = qT + (size_t)bh * NTOK * HD;
    const char* Kb = (const char*)(kT + (size_t)bh * NTOK * HD);
    const char* Vb = (const char*)(vT + (size_t)bh * NTOK * HD);

    bf16x8 qf[8];
    {
        const bf16_t* qrow = Q + (size_t)(q0 + wid * 32 + ql) * HD + hi * 8;
#pragma unroll
        for (int kc = 0; kc < 8; ++kc) qf[kc] = *(const bf16x8*)(qrow + kc * 16);
    }
    f32x16 oa[4];
#pragma unroll
    for (int df = 0; df < 4; ++df)
#pragma unroll
        for (int r = 0; r < 16; ++r) oa[df][r] = 0.f;
    float m_run = -1e30f, l_run = 0.f;
    const float L2E = 1.44269504089f;

    const int sw = (ql & 7) << 4;
    int xk[8];
#pragma unroll
    for (int kc = 0; kc < 8; ++kc) xk[kc] = (kc * 32 + hi * 16) ^ sw;
    const int krb0 = ql * 256, krb1 = (32 + ql) * 256;
    int vrb[4];
#pragma unroll
    for (int df = 0; df < 4; ++df) vrb[df] = 16384 + (df * 32 + ql) * 128;

    const char* kgp[4];
    const char* vgp[4];
    const int ldso[4] = {wid * 4096, wid * 4096 + 1024, wid * 4096 + 2048, wid * 4096 + 3072};
#pragma unroll
    for (int i = 0; i < 4; ++i) {
        int a = wid * 4096 + i * 1024 + lane * 16;
        int row = a >> 8;
        int col = (a & 255) ^ ((row & 7) << 4);
        kgp[i] = Kb + (size_t)row * 256 + col;
        int row2 = a >> 7;
        int col2 = (a & 127) ^ ((row2 & 7) << 4);
        vgp[i] = Vb + (size_t)row2 * (NTOK * 2) + col2;
    }

#pragma unroll
    for (int i = 0; i < 4; ++i) gload16(kgp[i], lds[0] + ldso[i]);
#pragma unroll
    for (int i = 0; i < 4; ++i) gload16(vgp[i], lds[0] + 16384 + ldso[i]);

#pragma unroll 2
    for (int t = 0; t < NTOK / 64; ++t) {
        const int buf = t & 1;
        if (t < NTOK / 64 - 1) {
            const size_t ko = (size_t)(t + 1) * 16384;
            const size_t vo = (size_t)(t + 1) * 128;
            char* db = lds[buf ^ 1];
#pragma unroll
            for (int i = 0; i < 4; ++i) gload16(kgp[i] + ko, db + ldso[i]);
#pragma unroll
            for (int i = 0; i < 4; ++i) gload16(vgp[i] + vo, db + 16384 + ldso[i]);
            asm volatile("s_waitcnt vmcnt(8)" ::: "memory");
        } else {
            asm volatile("s_waitcnt vmcnt(0)" ::: "memory");
        }
        __builtin_amdgcn_s_barrier();
        const char* Kl = lds[buf];

#pragma unroll
        for (int half = 0; half < 2; ++half) {
            const int krb = half ? krb1 : krb0;
            f32x16 s;
#pragma unroll
            for (int r = 0; r < 16; ++r) s[r] = 0.f;
#pragma unroll
            for (int kc = 0; kc < 8; ++kc) {
                bf16x8 kf = *(const bf16x8*)(Kl + krb + xk[kc]);
                s = __builtin_amdgcn_mfma_f32_32x32x16_bf16(kf, qf[kc], s, 0, 0, 0);
            }

            float m8[8];
#pragma unroll
            for (int r = 0; r < 8; ++r) m8[r] = fmaxf(s[r], s[r + 8]);
#pragma unroll
            for (int st = 4; st >= 1; st >>= 1)
#pragma unroll
                for (int r = 0; r < st; ++r) m8[r] = fmaxf(m8[r], m8[r + st]);
            float mx = fmaxf(m8[0], __shfl_xor(m8[0], 32));
            if (__any(mx - m_run > 8.f)) {
                float mn = fmaxf(m_run, mx);
                float resc = __expf(m_run - mn);
                l_run *= resc;
#pragma unroll
                for (int df = 0; df < 4; ++df) oa[df] *= resc;
                m_run = mn;
            }
            const float mb = m_run * L2E;
#pragma unroll
            for (int r = 0; r < 16; ++r) s[r] = exp2f(fmaf(s[r], L2E, -mb));
            {
                float u[8];
#pragma unroll
                for (int r = 0; r < 8; ++r) u[r] = s[r] + s[r + 8];
#pragma unroll
                for (int st = 4; st >= 1; st >>= 1)
#pragma unroll
                    for (int r = 0; r < st; ++r) u[r] += u[r + st];
                l_run += u[0];
            }
            unsigned int pk[8];
#pragma unroll
            for (int m = 0; m < 8; ++m) pk[m] = pack2bf(s[2 * m], s[2 * m + 1]);

#pragma unroll
            for (int c1 = 0; c1 < 2; ++c1) {
                unsigned int a0 = pk[4 * c1 + 0], b0 = pk[4 * c1 + 2];
                unsigned int a1 = pk[4 * c1 + 1], b1 = pk[4 * c1 + 3];
                asm("v_permlane32_swap_b32 %0, %1" : "+v"(a0), "+v"(b0));
                asm("v_permlane32_swap_b32 %0, %1" : "+v"(a1), "+v"(b1));
                union { unsigned int u[4]; bf16x8 v; } pb;
                pb.u[0] = a0; pb.u[1] = a1; pb.u[2] = b0; pb.u[3] = b1;
                const int kx = half * 2 + c1;
#pragma unroll
                for (int df = 0; df < 4; ++df) {
                    bf16x8 va = *(const bf16x8*)(Kl + vrb[df] + xk[kx]);
                    oa[df] = __builtin_amdgcn_mfma_f32_32x32x16_bf16(va, pb.v, oa[df], 0, 0, 0);
                }
            }
        }
        __builtin_amdgcn_s_barrier();
    }

    float lt = l_run + __shfl_xor(l_run, 32);
    float inv = 1.f / lt;
    bf16_t* Ot = (bf16_t*)((char*)lds + wid * 8704);
#pragma unroll
    for (int df = 0; df < 4; ++df)
#pragma unroll
        for (int rg = 0; rg < 4; ++rg) {
            bf16x4 w;
#pragma unroll
            for (int i = 0; i < 4; ++i) w[i] = (bf16_t)(oa[df][rg * 4 + i] * inv);
            int d0 = df * 32 + rg * 8 + hi * 4;
            *(bf16x4*)&Ot[ql * 136 + d0] = w;
        }
    __builtin_amdgcn_s_waitcnt(0);
    const int qloc = lane >> 1, half = lane & 1;
    const int b = bh >> 4, h = bh & 15;
    bf16_t* orow = outp + (size_t)(b * NTOK + q0 + wid * 32 + qloc) * HIDDEN + h * HD + half * 64;
    const bf16_t* src = Ot + qloc * 136 + half * 64;
#pragma unroll
    for (int c = 0; c < 8; ++c)
        *(bf16x8*)(orow + c * 8) = *(const bf16x8*)(src + c * 8);
}

extern "C" void kernel_launch(void* const* d_in, const int* in_sizes, int n_in,
                              void* d_out, int out_size, void* d_ws, size_t ws_size,
                              hipStream_t stream) {
    const float* x = (const float*)d_in[0];
    const float* w_qkv = (const float*)d_in[1];
    const float* b_qkv = (const float*)d_in[2];
    const float* w_proj = (const float*)d_in[3];
    const float* b_proj = (const float*)d_in[4];
    const int* Hp = (const int*)d_in[6];
    const int* Wp = (const int*)d_in[7];
    float* out = (float*)d_out;

    char* ws = (char*)d_ws;
    bf16_t* xb = (bf16_t*)(ws + 0);                       // 16 MiB  [4096][2048]
    bf16_t* wqkvT = (bf16_t*)(ws + 16777216);             // 24 MiB  [6144][2048]
    bf16_t* wprojT = (bf16_t*)(ws + 41943040);            // 8 MiB   [2048][2048]
    bf16_t* vT = (bf16_t*)(ws + 50331648);                // 16 MiB  [32][128][2048]
    bf16_t* attno = (bf16_t*)(ws + 67108864);             // 16 MiB  [4096][2048]
    float2* tab = (float2*)(ws + 83886080);               // 1 MiB   [2048][64]
    bf16_t* qTb = (bf16_t*)(ws + 100663296);              // 16 MiB  [32][2048][128]
    bf16_t* kTb = (bf16_t*)(ws + 117440512);              // 16 MiB

    cvt8_kernel<<<4096, 256, 0, stream>>>(x, xb, 1048576);
    cvtT_kernel<<<dim3(96, 32), 256, 0, stream>>>(w_qkv, wqkvT, 2048, 6144);
    cvtT_kernel<<<dim3(32, 32), 256, 0, stream>>>(w_proj, wprojT, 2048, 2048);
    rope_cs<<<512, 256, 0, stream>>>(Hp, Wp, tab);
    gemm_qkv<<<768, 256, 0, stream>>>(xb, wqkvT, b_qkv, tab, qTb, kTb, vT);
    attn_kernel<<<512, 256, 0, stream>>>(qTb, kTb, vT, attno);
    gemm_pipe_sq<<<512, 256, 0, stream>>>(attno, wprojT, b_proj, out, MROWS, HIDDEN, HIDDEN);
}

// Round 16
// 276.874 us; speedup vs baseline: 1.6030x; 1.0227x over previous
//
#include <hip/hip_runtime.h>
#include <hip/hip_bf16.h>

typedef __bf16 bf16_t;
typedef __bf16 bf16x8 __attribute__((ext_vector_type(8)));
typedef __bf16 bf16x4 __attribute__((ext_vector_type(4)));
typedef float f32x4 __attribute__((ext_vector_type(4)));
typedef float f32x16 __attribute__((ext_vector_type(16)));

#define HIDDEN 2048
#define NHEADS 16
#define HD 128
#define NTOK 2048
#define BATCH 2
#define MROWS (BATCH*NTOK)
#define QKVCOLS (3*HIDDEN)

__device__ __forceinline__ void gload16(const void* g, void* l) {
    __builtin_amdgcn_global_load_lds(
        (const __attribute__((address_space(1))) void*)g,
        (__attribute__((address_space(3))) void*)l,
        16, 0, 0);
}

__device__ __forceinline__ unsigned int pack2bf(float lo, float hi2) {
    union { bf16_t h[2]; unsigned int u; } t;
    t.h[0] = (bf16_t)lo; t.h[1] = (bf16_t)hi2;
    return t.u;
}

// ======== unified prep: cvt8(x) | cvtT(w_qkv) | cvtT(w_proj) | rope_cs ========
// blocks [0,4096): cvt8; [4096,7168): w_qkv T; [7168,8192): w_proj T; [8192,8704): cos/sin
__global__ __launch_bounds__(256) void prep_kernel(const float* __restrict__ x,
                                                   bf16_t* __restrict__ xb,
                                                   const float* __restrict__ w_qkv,
                                                   bf16_t* __restrict__ wqkvT,
                                                   const float* __restrict__ w_proj,
                                                   bf16_t* __restrict__ wprojT,
                                                   const int* __restrict__ Hp,
                                                   const int* __restrict__ Wp,
                                                   float2* __restrict__ tab) {
    __shared__ float t[64][65];
    const int blk = blockIdx.x, tid = threadIdx.x;

    if (blk < 4096) {
        // ---- fp32 -> bf16 elementwise (x), 8 per thread ----
        const size_t i = (size_t)blk * 256 + tid;
        const float4 a = *(const float4*)(x + i * 8);
        const float4 b = *(const float4*)(x + i * 8 + 4);
        bf16x8 r;
        r[0] = (bf16_t)a.x; r[1] = (bf16_t)a.y; r[2] = (bf16_t)a.z; r[3] = (bf16_t)a.w;
        r[4] = (bf16_t)b.x; r[5] = (bf16_t)b.y; r[6] = (bf16_t)b.z; r[7] = (bf16_t)b.w;
        *(bf16x8*)(xb + i * 8) = r;
        return;
    }
    if (blk < 8192) {
        // ---- fp32 [K][N] -> bf16 [N][K] transpose-convert ----
        const float* in;
        bf16_t* out;
        int n0, k0, N;
        if (blk < 7168) {
            const int bb = blk - 4096;            // 96 x 32 tiles
            in = w_qkv; out = wqkvT; N = 6144;
            n0 = (bb % 96) * 64; k0 = (bb / 96) * 64;
        } else {
            const int bb = blk - 7168;            // 32 x 32 tiles
            in = w_proj; out = wprojT; N = 2048;
            n0 = (bb % 32) * 64; k0 = (bb / 32) * 64;
        }
        const int c = tid & 63, r4 = tid >> 6;
#pragma unroll
        for (int rr = 0; rr < 64; rr += 4)
            t[rr + r4][c] = in[(size_t)(k0 + rr + r4) * N + n0 + c];
        __syncthreads();
#pragma unroll
        for (int rr = 0; rr < 64; rr += 4) {
            const int nn = rr + r4;
            out[(size_t)(n0 + nn) * 2048 + k0 + c] = (bf16_t)t[c][nn];
        }
        return;
    }
    // ---- cos/sin table ----
    const int idx = (blk - 8192) * 256 + tid;
    const int n = idx >> 6, j = idx & 63;
    const int Hh = *Hp, Ww = *Wp, HW = Hh * Ww;
    const int tt = n / HW, rem = n % HW;
    const int hh = rem / Ww, w = rem % Ww;
    float pos = (j < 16) ? (float)tt : (j < 40 ? (float)hh : (float)w);
    float inv = expf(-(float)j * (9.210340371976184f / 64.f));
    float ang = pos * inv;
    tab[idx] = make_float2(cosf(ang), sinf(ang));
}

// ======== QKV GEMM with fused RoPE + V-transpose epilogue (proven R15) ========
__global__ __launch_bounds__(256, 2) void gemm_qkv(const bf16_t* __restrict__ A,
                                                   const bf16_t* __restrict__ Bt,
                                                   const float* __restrict__ bias,
                                                   const float2* __restrict__ tab,
                                                   bf16_t* __restrict__ qT,
                                                   bf16_t* __restrict__ kT,
                                                   bf16_t* __restrict__ vT) {
    __shared__ __align__(16) char lds[3][24576];  // per buf: A 8KB | B 16KB
    const int M = MROWS, N = QKVCOLS, K = HIDDEN;
    const int NKT = K >> 5;
    const int tid = threadIdx.x, wid = tid >> 6, lane = tid & 63;
    const int lr = lane & 15, lg = lane >> 4;
    const int nwg = gridDim.x, cpx = nwg >> 3;
    const int bid = blockIdx.x;
    const int swz = (bid & 7) * cpx + (bid >> 3);
    const int ntm = M >> 7;
    const int m0 = (swz % ntm) * 128, n0 = (swz / ntm) * 256;

    const int sc = (((tid & 3) ^ ((tid >> 3) & 3)) << 4);
    const int srow = tid >> 2;
    const char* pA0 = (const char*)A + ((size_t)(m0 + srow) * K) * 2 + sc;
    const char* pA1 = (const char*)A + ((size_t)(m0 + srow + 64) * K) * 2 + sc;
    const char* pB0 = (const char*)Bt + ((size_t)(n0 + srow) * K) * 2 + sc;
    const char* pB1 = (const char*)Bt + ((size_t)(n0 + srow + 64) * K) * 2 + sc;
    const char* pB2 = (const char*)Bt + ((size_t)(n0 + srow + 128) * K) * 2 + sc;
    const char* pB3 = (const char*)Bt + ((size_t)(n0 + srow + 192) * K) * 2 + sc;
    const int xoff = lr * 64 + ((lg ^ ((lr >> 1) & 3)) << 4);

    auto stage3a = [&](int kb, char* bp) {
        gload16(pA0 + kb, bp + tid * 16);
        gload16(pA1 + kb, bp + tid * 16 + 4096);
        gload16(pB0 + kb, bp + 8192 + tid * 16);
    };
    auto stage3b = [&](int kb, char* bp) {
        gload16(pB1 + kb, bp + 8192 + tid * 16 + 4096);
        gload16(pB2 + kb, bp + 8192 + tid * 16 + 8192);
        gload16(pB3 + kb, bp + 8192 + tid * 16 + 12288);
    };

    f32x4 acc[8][4];
#pragma unroll
    for (int m = 0; m < 8; ++m)
#pragma unroll
        for (int n = 0; n < 4; ++n) acc[m][n] = f32x4{0.f, 0.f, 0.f, 0.f};

    stage3a(0, lds[0]); stage3b(0, lds[0]);
    stage3a(64, lds[1]); stage3b(64, lds[1]);
    asm volatile("s_waitcnt vmcnt(6)" ::: "memory");
    __builtin_amdgcn_s_barrier();

    int cur = 0;
    for (int kt = 0; kt < NKT; ++kt) {
        const char* Al = lds[cur];
        const char* Bl = Al + 8192;
        int sb = cur + 2; if (sb >= 3) sb -= 3;
        char* sp = lds[sb];
        const bool st = (kt + 2) < NKT;
        const int kb = (kt + 2) << 6;

        bf16x8 bfr[4], afr[4];
#pragma unroll
        for (int n = 0; n < 4; ++n)
            bfr[n] = *(const bf16x8*)(Bl + wid * 4096 + n * 1024 + xoff);
#pragma unroll
        for (int m = 0; m < 4; ++m)
            afr[m] = *(const bf16x8*)(Al + m * 1024 + xoff);
        if (st) stage3a(kb, sp);
        __builtin_amdgcn_s_setprio(1);
#pragma unroll
        for (int m = 0; m < 4; ++m)
#pragma unroll
            for (int n = 0; n < 4; ++n)
                acc[m][n] = __builtin_amdgcn_mfma_f32_16x16x32_bf16(afr[m], bfr[n], acc[m][n], 0, 0, 0);
        __builtin_amdgcn_s_setprio(0);

#pragma unroll
        for (int m = 0; m < 4; ++m)
            afr[m] = *(const bf16x8*)(Al + (m + 4) * 1024 + xoff);
        if (st) stage3b(kb, sp);
        __builtin_amdgcn_s_setprio(1);
#pragma unroll
        for (int m = 0; m < 4; ++m)
#pragma unroll
            for (int n = 0; n < 4; ++n)
                acc[m + 4][n] = __builtin_amdgcn_mfma_f32_16x16x32_bf16(afr[m], bfr[n], acc[m + 4][n], 0, 0, 0);
        __builtin_amdgcn_s_setprio(0);

        if (kt < NKT - 1) {
            if (st) asm volatile("s_waitcnt vmcnt(6)" ::: "memory");
            else    asm volatile("s_waitcnt vmcnt(0)" ::: "memory");
            __builtin_amdgcn_s_barrier();
        }
        cur = cur + 1; if (cur >= 3) cur -= 3;
    }

    // ---- fused epilogue: acc -> LDS tile -> RoPE / transpose stores ----
    __syncthreads();
    bf16_t* T = (bf16_t*)lds;              // [128][264] = 67584 B < 73728 B
    const int TW = 264;
    float bvals[4];
#pragma unroll
    for (int n = 0; n < 4; ++n) bvals[n] = bias[n0 + wid * 64 + n * 16 + lr];
#pragma unroll
    for (int m = 0; m < 8; ++m)
#pragma unroll
        for (int n = 0; n < 4; ++n)
#pragma unroll
            for (int i = 0; i < 4; ++i)
                T[(m * 16 + lg * 4 + i) * TW + wid * 64 + n * 16 + lr] =
                    (bf16_t)(acc[m][n][i] + bvals[n]);
    __syncthreads();

    const int which = n0 >> 11;            // 0=q, 1=k, 2=v
    const int hbase = (n0 & 2047) >> 7;
    const int b = m0 >> 11, tokbase = m0 & 2047;

    if (which < 2) {
        bf16_t* dst = which ? kT : qT;
        const float qs = which ? 1.f : 0.08838834764831845f;
        const int jg = tid & 7, rl = tid >> 3;
#pragma unroll
        for (int p = 0; p < 4; ++p) {
            const int tok = p * 32 + rl;
            const int n_tok = tokbase + tok;
            union { float4 f4[4]; float2 f2[8]; } cs;
            const float4* cp4 = (const float4*)(tab + (size_t)n_tok * 64 + jg * 8);
#pragma unroll
            for (int i = 0; i < 4; ++i) cs.f4[i] = cp4[i];
#pragma unroll
            for (int h2 = 0; h2 < 2; ++h2) {
                bf16x8 lo = *(const bf16x8*)&T[tok * TW + h2 * 128 + jg * 8];
                bf16x8 hi = *(const bf16x8*)&T[tok * TW + h2 * 128 + 64 + jg * 8];
                bf16x8 olo, ohi;
#pragma unroll
                for (int i = 0; i < 8; ++i) {
                    float c = cs.f2[i].x, s = cs.f2[i].y;
                    float a = (float)lo[i], bb = (float)hi[i];
                    olo[i] = (bf16_t)((a * c - bb * s) * qs);
                    ohi[i] = (bf16_t)((bb * c + a * s) * qs);
                }
                const int bh = b * NHEADS + hbase + h2;
                const size_t o = ((size_t)bh * NTOK + n_tok) * HD + jg * 8;
                *(bf16x8*)(dst + o) = olo;
                *(bf16x8*)(dst + o + 64) = ohi;
            }
        }
    } else {
        const int d = tid >> 1, th = (tid & 1) * 64;
#pragma unroll
        for (int h2 = 0; h2 < 2; ++h2) {
            const int bh = b * NHEADS + hbase + h2;
            bf16_t* orow = vT + ((size_t)bh * HD + d) * NTOK + tokbase + th;
#pragma unroll
            for (int c8 = 0; c8 < 8; ++c8) {
                bf16x8 tmp;
#pragma unroll
                for (int e = 0; e < 8; ++e)
                    tmp[e] = T[(th + c8 * 8 + e) * TW + h2 * 128 + d];
                *(bf16x8*)(orow + c8 * 8) = tmp;
            }
        }
    }
}

// ---------------- 3-buffer pipelined GEMM: 128x128 tile (out-proj, grid 512) ----------------
__global__ __launch_bounds__(256, 2) void gemm_pipe_sq(const bf16_t* __restrict__ A,
                                                       const bf16_t* __restrict__ Bt,
                                                       const float* __restrict__ bias,
                                                       float* __restrict__ C,
                                                       int M, int N, int K) {
    __shared__ __align__(16) char lds[3][16384];  // per buf: A 8KB | B 8KB
    const int NKT = K >> 5;
    const int tid = threadIdx.x, wid = tid >> 6, lane = tid & 63;
    const int lr = lane & 15, lg = lane >> 4;
    const int wr = wid >> 1, wc = wid & 1;
    const int nwg = gridDim.x, cpx = nwg >> 3;
    const int bid = blockIdx.x;
    const int swz = (bid & 7) * cpx + (bid >> 3);
    const int ntm = M >> 7;
    const int m0 = (swz % ntm) * 128, n0 = (swz / ntm) * 128;

    const int sc = (((tid & 3) ^ ((tid >> 3) & 3)) << 4);
    const int srow = tid >> 2;
    const char* pA0 = (const char*)A + ((size_t)(m0 + srow) * K) * 2 + sc;
    const char* pA1 = (const char*)A + ((size_t)(m0 + srow + 64) * K) * 2 + sc;
    const char* pB0 = (const char*)Bt + ((size_t)(n0 + srow) * K) * 2 + sc;
    const char* pB1 = (const char*)Bt + ((size_t)(n0 + srow + 64) * K) * 2 + sc;
    const int xoff = lr * 64 + ((lg ^ ((lr >> 1) & 3)) << 4);

    auto stage4 = [&](int kb, char* bp) {
        gload16(pA0 + kb, bp + tid * 16);
        gload16(pA1 + kb, bp + tid * 16 + 4096);
        gload16(pB0 + kb, bp + 8192 + tid * 16);
        gload16(pB1 + kb, bp + 8192 + tid * 16 + 4096);
    };

    f32x4 acc[4][4];
#pragma unroll
    for (int m = 0; m < 4; ++m)
#pragma unroll
        for (int n = 0; n < 4; ++n) acc[m][n] = f32x4{0.f, 0.f, 0.f, 0.f};

    stage4(0, lds[0]);
    stage4(64, lds[1]);
    asm volatile("s_waitcnt vmcnt(4)" ::: "memory");
    __builtin_amdgcn_s_barrier();

    int cur = 0;
    for (int kt = 0; kt < NKT; ++kt) {
        const char* Al = lds[cur];
        const char* Bl = Al + 8192;
        int sb = cur + 2; if (sb >= 3) sb -= 3;
        char* sp = lds[sb];
        const bool st = (kt + 2) < NKT;

        bf16x8 bfr[4], afr[4];
#pragma unroll
        for (int n = 0; n < 4; ++n)
            bfr[n] = *(const bf16x8*)(Bl + wc * 4096 + n * 1024 + xoff);
#pragma unroll
        for (int m = 0; m < 4; ++m)
            afr[m] = *(const bf16x8*)(Al + wr * 4096 + m * 1024 + xoff);
        if (st) stage4((kt + 2) << 6, sp);
        __builtin_amdgcn_s_setprio(1);
#pragma unroll
        for (int m = 0; m < 4; ++m)
#pragma unroll
            for (int n = 0; n < 4; ++n)
                acc[m][n] = __builtin_amdgcn_mfma_f32_16x16x32_bf16(afr[m], bfr[n], acc[m][n], 0, 0, 0);
        __builtin_amdgcn_s_setprio(0);

        if (kt < NKT - 1) {
            if (st) asm volatile("s_waitcnt vmcnt(4)" ::: "memory");
            else    asm volatile("s_waitcnt vmcnt(0)" ::: "memory");
            __builtin_amdgcn_s_barrier();
        }
        cur = cur + 1; if (cur >= 3) cur -= 3;
    }

    float bvals[4];
#pragma unroll
    for (int n = 0; n < 4; ++n) bvals[n] = bias[n0 + wc * 64 + n * 16 + lr];
#pragma unroll
    for (int m = 0; m < 4; ++m) {
        const size_t row = (size_t)(m0 + wr * 64 + m * 16 + lg * 4);
#pragma unroll
        for (int n = 0; n < 4; ++n) {
            const int col = n0 + wc * 64 + n * 16 + lr;
#pragma unroll
            for (int i = 0; i < 4; ++i)
                C[(row + i) * N + col] = acc[m][n][i] + bvals[n];
        }
    }
}

// ---------------- flash attention (proven ~114us, frozen) ----------------
__global__ __launch_bounds__(256, 2) void attn_kernel(const bf16_t* __restrict__ qT,
                                                      const bf16_t* __restrict__ kT,
                                                      const bf16_t* __restrict__ vT,
                                                      bf16_t* __restrict__ outp) {
    __shared__ __align__(16) char lds[2][32768];  // per buf: K tile 16KB | V tile 16KB
    const int B = blockIdx.x;
    const int xcd = B & 7, jj = B >> 3;
    const int bh = xcd * 4 + (jj >> 4);
    const int q0 = (jj & 15) * 128;
    const int tid = threadIdx.x, wid = tid >> 6, lane = tid & 63;
    const int ql = lane & 31, hi = lane >> 5;

    const bf16_t* Q = qT + (size_t)bh * NTOK * HD;
    const char* Kb = (const char*)(kT + (size_t)bh * NTOK * HD);
    const char* Vb = (const char*)(vT + (size_t)bh * NTOK * HD);

    bf16x8 qf[8];
    {
        const bf16_t* qrow = Q + (size_t)(q0 + wid * 32 + ql) * HD + hi * 8;
#pragma unroll
        for (int kc = 0; kc < 8; ++kc) qf[kc] = *(const bf16x8*)(qrow + kc * 16);
    }
    f32x16 oa[4];
#pragma unroll
    for (int df = 0; df < 4; ++df)
#pragma unroll
        for (int r = 0; r < 16; ++r) oa[df][r] = 0.f;
    float m_run = -1e30f, l_run = 0.f;
    const float L2E = 1.44269504089f;

    const int sw = (ql & 7) << 4;
    int xk[8];
#pragma unroll
    for (int kc = 0; kc < 8; ++kc) xk[kc] = (kc * 32 + hi * 16) ^ sw;
    const int krb0 = ql * 256, krb1 = (32 + ql) * 256;
    int vrb[4];
#pragma unroll
    for (int df = 0; df < 4; ++df) vrb[df] = 16384 + (df * 32 + ql) * 128;

    const char* kgp[4];
    const char* vgp[4];
    const int ldso[4] = {wid * 4096, wid * 4096 + 1024, wid * 4096 + 2048, wid * 4096 + 3072};
#pragma unroll
    for (int i = 0; i < 4; ++i) {
        int a = wid * 4096 + i * 1024 + lane * 16;
        int row = a >> 8;
        int col = (a & 255) ^ ((row & 7) << 4);
        kgp[i] = Kb + (size_t)row * 256 + col;
        int row2 = a >> 7;
        int col2 = (a & 127) ^ ((row2 & 7) << 4);
        vgp[i] = Vb + (size_t)row2 * (NTOK * 2) + col2;
    }

#pragma unroll
    for (int i = 0; i < 4; ++i) gload16(kgp[i], lds[0] + ldso[i]);
#pragma unroll
    for (int i = 0; i < 4; ++i) gload16(vgp[i], lds[0] + 16384 + ldso[i]);

#pragma unroll 2
    for (int t = 0; t < NTOK / 64; ++t) {
        const int buf = t & 1;
        if (t < NTOK / 64 - 1) {
            const size_t ko = (size_t)(t + 1) * 16384;
            const size_t vo = (size_t)(t + 1) * 128;
            char* db = lds[buf ^ 1];
#pragma unroll
            for (int i = 0; i < 4; ++i) gload16(kgp[i] + ko, db + ldso[i]);
#pragma unroll
            for (int i = 0; i < 4; ++i) gload16(vgp[i] + vo, db + 16384 + ldso[i]);
            asm volatile("s_waitcnt vmcnt(8)" ::: "memory");
        } else {
            asm volatile("s_waitcnt vmcnt(0)" ::: "memory");
        }
        __builtin_amdgcn_s_barrier();
        const char* Kl = lds[buf];

#pragma unroll
        for (int half = 0; half < 2; ++half) {
            const int krb = half ? krb1 : krb0;
            f32x16 s;
#pragma unroll
            for (int r = 0; r < 16; ++r) s[r] = 0.f;
#pragma unroll
            for (int kc = 0; kc < 8; ++kc) {
                bf16x8 kf = *(const bf16x8*)(Kl + krb + xk[kc]);
                s = __builtin_amdgcn_mfma_f32_32x32x16_bf16(kf, qf[kc], s, 0, 0, 0);
            }

            float m8[8];
#pragma unroll
            for (int r = 0; r < 8; ++r) m8[r] = fmaxf(s[r], s[r + 8]);
#pragma unroll
            for (int st = 4; st >= 1; st >>= 1)
#pragma unroll
                for (int r = 0; r < st; ++r) m8[r] = fmaxf(m8[r], m8[r + st]);
            float mx = fmaxf(m8[0], __shfl_xor(m8[0], 32));
            if (__any(mx - m_run > 8.f)) {
                float mn = fmaxf(m_run, mx);
                float resc = __expf(m_run - mn);
                l_run *= resc;
#pragma unroll
                for (int df = 0; df < 4; ++df) oa[df] *= resc;
                m_run = mn;
            }
            const float mb = m_run * L2E;
#pragma unroll
            for (int r = 0; r < 16; ++r) s[r] = exp2f(fmaf(s[r], L2E, -mb));
            {
                float u[8];
#pragma unroll
                for (int r = 0; r < 8; ++r) u[r] = s[r] + s[r + 8];
#pragma unroll
                for (int st = 4; st >= 1; st >>= 1)
#pragma unroll
                    for (int r = 0; r < st; ++r) u[r] += u[r + st];
                l_run += u[0];
            }
            unsigned int pk[8];
#pragma unroll
            for (int m = 0; m < 8; ++m) pk[m] = pack2bf(s[2 * m], s[2 * m + 1]);

#pragma unroll
            for (int c1 = 0; c1 < 2; ++c1) {
                unsigned int a0 = pk[4 * c1 + 0], b0 = pk[4 * c1 + 2];
                unsigned int a1 = pk[4 * c1 + 1], b1 = pk[4 * c1 + 3];
                asm("v_permlane32_swap_b32 %0, %1" : "+v"(a0), "+v"(b0));
                asm("v_permlane32_swap_b32 %0, %1" : "+v"(a1), "+v"(b1));
                union { unsigned int u[4]; bf16x8 v; } pb;
                pb.u[0] = a0; pb.u[1] = a1; pb.u[2] = b0; pb.u[3] = b1;
                const int kx = half * 2 + c1;
#pragma unroll
                for (int df = 0; df < 4; ++df) {
                    bf16x8 va = *(const bf16x8*)(Kl + vrb[df] + xk[kx]);
                    oa[df] = __builtin_amdgcn_mfma_f32_32x32x16_bf16(va, pb.v, oa[df], 0, 0, 0);
                }
            }
        }
        __builtin_amdgcn_s_barrier();
    }

    float lt = l_run + __shfl_xor(l_run, 32);
    float inv = 1.f / lt;
    bf16_t* Ot = (bf16_t*)((char*)lds + wid * 8704);
#pragma unroll
    for (int df = 0; df < 4; ++df)
#pragma unroll
        for (int rg = 0; rg < 4; ++rg) {
            bf16x4 w;
#pragma unroll
            for (int i = 0; i < 4; ++i) w[i] = (bf16_t)(oa[df][rg * 4 + i] * inv);
            int d0 = df * 32 + rg * 8 + hi * 4;
            *(bf16x4*)&Ot[ql * 136 + d0] = w;
        }
    __builtin_amdgcn_s_waitcnt(0);
    const int qloc = lane >> 1, half = lane & 1;
    const int b = bh >> 4, h = bh & 15;
    bf16_t* orow = outp + (size_t)(b * NTOK + q0 + wid * 32 + qloc) * HIDDEN + h * HD + half * 64;
    const bf16_t* src = Ot + qloc * 136 + half * 64;
#pragma unroll
    for (int c = 0; c < 8; ++c)
        *(bf16x8*)(orow + c * 8) = *(const bf16x8*)(src + c * 8);
}

extern "C" void kernel_launch(void* const* d_in, const int* in_sizes, int n_in,
                              void* d_out, int out_size, void* d_ws, size_t ws_size,
                              hipStream_t stream) {
    const float* x = (const float*)d_in[0];
    const float* w_qkv = (const float*)d_in[1];
    const float* b_qkv = (const float*)d_in[2];
    const float* w_proj = (const float*)d_in[3];
    const float* b_proj = (const float*)d_in[4];
    const int* Hp = (const int*)d_in[6];
    const int* Wp = (const int*)d_in[7];
    float* out = (float*)d_out;

    char* ws = (char*)d_ws;
    bf16_t* xb = (bf16_t*)(ws + 0);                       // 16 MiB  [4096][2048]
    bf16_t* wqkvT = (bf16_t*)(ws + 16777216);             // 24 MiB  [6144][2048]
    bf16_t* wprojT = (bf16_t*)(ws + 41943040);            // 8 MiB   [2048][2048]
    bf16_t* vT = (bf16_t*)(ws + 50331648);                // 16 MiB  [32][128][2048]
    bf16_t* attno = (bf16_t*)(ws + 67108864);             // 16 MiB  [4096][2048]
    float2* tab = (float2*)(ws + 83886080);               // 1 MiB   [2048][64]
    bf16_t* qTb = (bf16_t*)(ws + 100663296);              // 16 MiB  [32][2048][128]
    bf16_t* kTb = (bf16_t*)(ws + 117440512);              // 16 MiB

    prep_kernel<<<8704, 256, 0, stream>>>(x, xb, w_qkv, wqkvT, w_proj, wprojT, Hp, Wp, tab);
    gemm_qkv<<<768, 256, 0, stream>>>(xb, wqkvT, b_qkv, tab, qTb, kTb, vT);
    attn_kernel<<<512, 256, 0, stream>>>(qTb, kTb, vT, attno);
    gemm_pipe_sq<<<512, 256, 0, stream>>>(attno, wprojT, b_proj, out, MROWS, HIDDEN, HIDDEN);
}